// Round 13
// baseline (257.382 us; speedup 1.0000x reference)
//
#include <hip/hip_runtime.h>
#include <math.h>

constexpr int B    = 4;
constexpr int NPTS = 4096;
constexpr int NTOT = B * NPTS;
constexpr int CIN  = 9;
constexpr int C0   = 18;
constexpr int KNB  = 8;
constexpr int HID  = 128;
constexpr int QR   = 64;    // q rows per fmha block
constexpr int KC   = 32;    // m per fmha tile (8KB K + 8KB V tiles)
constexpr int NSPL = 4;     // fmha KV splits
constexpr float EPSF = 1e-5f;

using f32x4  = __attribute__((ext_vector_type(4))) float;
using bf16x8 = __attribute__((ext_vector_type(8))) short;

__device__ inline unsigned short f2bf(float f) {
    unsigned int x = __float_as_uint(f);
    unsigned int r = (x + 0x7fffu + ((x >> 16) & 1u)) >> 16;
    return (unsigned short)r;
}
__device__ inline float bf2f(unsigned short u) {
    return __uint_as_float(((unsigned int)u) << 16);
}
__device__ inline unsigned int pack2(float a, float b) {
    return (unsigned int)f2bf(a) | ((unsigned int)f2bf(b) << 16);
}
// HW packed f32->bf16 (RNE), 1 instr per 2 values
__device__ inline unsigned int cvtpk(float lo, float hi) {
    unsigned int r;
    asm("v_cvt_pk_bf16_f32 %0, %1, %2" : "=v"(r) : "v"(lo), "v"(hi));
    return r;
}

#define GLD_LDS16(g, l) __builtin_amdgcn_global_load_lds( \
    (const __attribute__((address_space(1))) void*)(g),   \
    (__attribute__((address_space(3))) void*)(l), 16, 0, 0)

// ---------------- prep: weight pack f32->bf16 (7 segments) + xyz pack ----------------
__global__ __launch_bounds__(256) void prep_kernel(const float* __restrict__ x,
                                                   float4* __restrict__ xyzw,
                                                   const float* __restrict__ w2,
                                                   const float* __restrict__ w3,
                                                   const float* __restrict__ qw,
                                                   const float* __restrict__ kw,
                                                   const float* __restrict__ vw,
                                                   const float* __restrict__ fw,
                                                   const float* __restrict__ aw1,
                                                   unsigned short* __restrict__ dst) {
    const int i = blockIdx.x * 256 + threadIdx.x;   // 188416 total
    if (i < NTOT) {
        const float* xp = x + (size_t)i * CIN;
        const float a = xp[0], b = xp[1], c = xp[2];
        xyzw[i] = make_float4(a, b, c, a * a + b * b + c * c);
    }
    const float* src;
    int off;
    if      (i <   8192) { src = w2;  off = 0; }
    else if (i <  40960) { src = w3;  off = 8192; }
    else if (i <  73728) { src = qw;  off = 40960; }
    else if (i < 106496) { src = kw;  off = 73728; }
    else if (i < 139264) { src = vw;  off = 106496; }
    else if (i < 172032) { src = fw;  off = 139264; }
    else                 { src = aw1; off = 172032; }
    dst[i] = f2bf(src[i - off]);
}

// ---------------- KNN v5: packed u32 (dist20|idx12) keys ----------------
__global__ __launch_bounds__(256) void knn3_kernel(const float* __restrict__ x,
                                                   const float4* __restrict__ xyzw,
                                                   float* __restrict__ h0) {
    __shared__ __align__(16) char lds[16384];
    const int tid = threadIdx.x;
    const int w = tid >> 6, l = tid & 63;
    const int b  = blockIdx.x >> 9;
    const int p0 = (blockIdx.x & 511) << 3;
    const int c  = l & 31;
    const int n  = p0 + w * 2 + (l >> 5);
    const float4* xb4 = xyzw + (size_t)b * NPTS;

    const float4 q4 = xb4[n];
    const float qx = q4.x, qy = q4.y, qz = q4.z, sqn = q4.w;

    unsigned int bd[KNB];
#pragma unroll
    for (int i = 0; i < KNB; ++i) bd[i] = 0xFFFFFFFFu;

    auto stage = [&](int buf, int t) {
#pragma unroll
        for (int i = 0; i < 2; ++i) {
            const int idx = i * 256 + w * 64 + l;
            const int m   = idx ^ ((idx >> 4) & 7);
            GLD_LDS16(xb4 + (size_t)t * 512 + m, lds + buf * 8192 + i * 4096 + w * 1024);
        }
    };

    stage(0, 0);
    for (int t = 0; t < 8; ++t) {
        const int cur = t & 1;
        __syncthreads();
        if (t < 7) stage(cur ^ 1, t + 1);

        const char* buf = lds + cur * 8192 + c * 256;
        const int mbase = t * 512 + c * 16;
        const int cswz  = (c & 7) << 4;
#pragma unroll 4
        for (int j = 0; j < 16; ++j) {
            const float4 f4 = *(const float4*)(buf + ((j << 4) ^ cswz));
            const float tt = fmaf(qx, f4.x, fmaf(qy, f4.y, qz * f4.z));
            const float d2 = fmaxf(fmaf(-2.0f, tt, sqn + f4.w), 0.f);
            const int m = mbase + j;
            unsigned int key = (__float_as_uint(d2) & 0xFFFFF000u) | (unsigned int)m;
            if (m == n) key = 0xFFFFFFFFu;
            bd[KNB - 1] = min(bd[KNB - 1], key);
#pragma unroll
            for (int s = KNB - 1; s > 0; --s) {
                const unsigned int lo = min(bd[s - 1], bd[s]);
                const unsigned int hi = max(bd[s - 1], bd[s]);
                bd[s - 1] = lo; bd[s] = hi;
            }
        }
    }

    unsigned int res[KNB];
#pragma unroll
    for (int r = 0; r < KNB; ++r) {
        unsigned int v = bd[0];
#pragma unroll
        for (int mask = 16; mask > 0; mask >>= 1)
            v = min(v, (unsigned int)__shfl_xor((int)v, mask));
        res[r] = v;
        if (bd[0] == v) {
#pragma unroll
            for (int s = 0; s < KNB - 1; ++s) bd[s] = bd[s + 1];
            bd[KNB - 1] = 0xFFFFFFFFu;
        }
    }

    const int c8 = c & 7;
    unsigned int kk = res[0];
#pragma unroll
    for (int k = 1; k < KNB; ++k) kk = (c8 == k) ? res[k] : kk;
    const int nb = (int)(kk & 0xFFFu);
    const float* xb = x + (size_t)b * NPTS * CIN;
    float nv[CIN];
    const float* nbp = xb + (size_t)nb * CIN;
#pragma unroll
    for (int ch = 0; ch < CIN; ++ch) nv[ch] = nbp[ch];
#pragma unroll
    for (int d = 1; d < 8; d <<= 1) {
#pragma unroll
        for (int ch = 0; ch < CIN; ++ch) nv[ch] += __shfl_xor(nv[ch], d);
    }
    const int ch = min(c, 8);
    float nvc = nv[0];
#pragma unroll
    for (int k = 1; k < CIN; ++k) nvc = (ch == k) ? nv[k] : nvc;
    if (c < 9) {
        const float xv = xb[(size_t)n * CIN + ch];
        h0[((size_t)b * C0 + ch) * NPTS + n]       = nvc * 0.125f - xv;
        h0[((size_t)b * C0 + CIN + ch) * NPTS + n] = xv;
    }
}

// ---------------- layer-1 conv (fp32, C=18) + partial stats ----------------
__global__ __launch_bounds__(256) void conv1_kernel(const float* __restrict__ X,
                                                    const float* __restrict__ W,
                                                    const float* __restrict__ bias,
                                                    float* __restrict__ Y,
                                                    float* __restrict__ parts) {
    __shared__ float Ws[16 * C0];
    const int b  = blockIdx.z;
    const int o_base = blockIdx.y * 16;
    const int l  = threadIdx.x & 63;
    const int n  = blockIdx.x * 64 + l;
    const int og = threadIdx.x >> 6;
    for (int i = threadIdx.x; i < 16 * C0; i += 256)
        Ws[i] = W[(size_t)o_base * C0 + i];
    __syncthreads();
    float acc[4] = {0.f, 0.f, 0.f, 0.f};
    const float* Xp = X + (size_t)b * C0 * NPTS + n;
    for (int c = 0; c < C0; ++c) {
        const float xv = Xp[(size_t)c * NPTS];
#pragma unroll
        for (int i = 0; i < 4; ++i)
            acc[i] = fmaf(Ws[(og * 4 + i) * C0 + c], xv, acc[i]);
    }
    f32x4 v;
#pragma unroll
    for (int i = 0; i < 4; ++i) v[i] = acc[i] + bias[o_base + og * 4 + i];
    *(f32x4*)(Y + ((size_t)b * NPTS + n) * 64 + o_base + og * 4) = v;
    float s1[4], s2[4];
#pragma unroll
    for (int i = 0; i < 4; ++i) { s1[i] = v[i]; s2[i] = v[i] * v[i]; }
#pragma unroll
    for (int d = 1; d < 64; d <<= 1) {
#pragma unroll
        for (int i = 0; i < 4; ++i) {
            s1[i] += __shfl_xor(s1[i], d);
            s2[i] += __shfl_xor(s2[i], d);
        }
    }
    if (l == 0) {
        const int rg = blockIdx.z * 64 + blockIdx.x;
#pragma unroll
        for (int i = 0; i < 4; ++i) {
            const int ch = o_base + og * 4 + i;
            parts[ch * 256 + rg]            = s1[i];
            parts[64 * 256 + ch * 256 + rg] = s2[i];
        }
    }
}

// ---------------- finalize stats ----------------
__global__ __launch_bounds__(64) void finstats_kernel(const float* __restrict__ parts,
                                                      float* __restrict__ mstats, int O) {
    const int ch = blockIdx.x, l = threadIdx.x;
    const f32x4 a1 = *(const f32x4*)(parts + (size_t)ch * 256 + l * 4);
    const f32x4 a2 = *(const f32x4*)(parts + (size_t)O * 256 + (size_t)ch * 256 + l * 4);
    float s1 = (a1[0] + a1[1]) + (a1[2] + a1[3]);
    float s2 = (a2[0] + a2[1]) + (a2[2] + a2[3]);
#pragma unroll
    for (int d = 1; d < 64; d <<= 1) {
        s1 += __shfl_xor(s1, d);
        s2 += __shfl_xor(s2, d);
    }
    if (l == 0) {
        const float mean = s1 * (1.0f / NTOT);
        const float var  = s2 * (1.0f / NTOT) - mean * mean;
        mstats[ch]     = mean;
        mstats[O + ch] = rsqrtf(var + EPSF);
    }
}

// ---------------- BN apply + ReLU -> bf16 ----------------
__global__ __launch_bounds__(256) void bnapply_kernel(const float* __restrict__ Y,
                                                      const float* __restrict__ mstats,
                                                      const float* __restrict__ g,
                                                      const float* __restrict__ be,
                                                      unsigned short* __restrict__ Yb,
                                                      int O) {
    const size_t i4 = (size_t)blockIdx.x * 256 + threadIdx.x;
    const int cbase = (int)((i4 * 4) & (O - 1));
    const f32x4 v = *(const f32x4*)(Y + i4 * 4);
    ushort4 pk;
    unsigned short* pp = (unsigned short*)&pk;
#pragma unroll
    for (int r = 0; r < 4; ++r) {
        const int c = cbase + r;
        const float y = fmaxf(g[c] * mstats[O + c] * (v[r] - mstats[c]) + be[c], 0.f);
        pp[r] = f2bf(y);
    }
    *(ushort4*)(Yb + i4 * 4) = pk;
}

// ---------------- bf16 MFMA GEMM ----------------
template <int C, int EPI>
__global__ __launch_bounds__(256) void gemm_kernel(const unsigned short* __restrict__ A,
                                                   const unsigned short* __restrict__ Wb,
                                                   const float* __restrict__ bias,
                                                   const unsigned short* __restrict__ resid,
                                                   void* __restrict__ Yv, int O,
                                                   float* __restrict__ parts) {
    constexpr int RB = 2 * C;
    constexpr int SLOTS = C / 8;
    __shared__ __align__(16) char ldsW[64 * RB];
    const int tid = threadIdx.x;
    const int w = tid >> 6, l = tid & 63;
    const int lg = l >> 4, lq = l & 15;
    const int n0 = blockIdx.x * 64;
    const int o0 = blockIdx.y * 64;

#pragma unroll
    for (int i = 0; i < C / 32; ++i) {
        const int idx = i * 256 + tid;
        const int m  = idx / SLOTS;
        const int sl = (idx % SLOTS) ^ (m & 7);
        GLD_LDS16(Wb + (size_t)(o0 + m) * C + sl * 8, ldsW + (i * 256 + w * 64) * 16);
    }

    const int nr = n0 + w * 16 + lq;
    const unsigned short* Ap = A + (size_t)nr * C + lg * 8;
    f32x4 acc[4];
#pragma unroll
    for (int os = 0; os < 4; ++os) acc[os] = {0.f, 0.f, 0.f, 0.f};
    __syncthreads();

#pragma unroll
    for (int ks = 0; ks < C / 32; ++ks) {
        const bf16x8 af = *(const bf16x8*)(Ap + ks * 32);
#pragma unroll
        for (int os = 0; os < 4; ++os) {
            const int row = os * 16 + lq;
            const bf16x8 wf = *(const bf16x8*)(ldsW + ((row * RB + ks * 64 + lg * 16) ^ ((lq & 7) << 4)));
            acc[os] = __builtin_amdgcn_mfma_f32_16x16x32_bf16(wf, af, acc[os], 0, 0, 0);
        }
    }

    f32x4 vv[4];
    float dotacc = 0.f;
#pragma unroll
    for (int os = 0; os < 4; ++os) {
        const int ob = o0 + os * 16 + lg * 4;
        const f32x4 bv = *(const f32x4*)(bias + ob);
#pragma unroll
        for (int r = 0; r < 4; ++r) vv[os][r] = acc[os][r] + bv[r];
        if (EPI == 0) {
            *(f32x4*)((float*)Yv + (size_t)nr * O + ob) = vv[os];
        } else if (EPI == 4) {
            unsigned short* Y = (unsigned short*)Yv;
            const int bb = nr >> 12, n = nr & (NPTS - 1);
#pragma unroll
            for (int r = 0; r < 4; ++r)
                Y[((size_t)bb * HID + ob + r) * NPTS + n] = f2bf(vv[os][r]);
        } else if (EPI == 5) {
            const f32x4 w2v = *(const f32x4*)((const float*)resid + ob);
#pragma unroll
            for (int r = 0; r < 4; ++r)
                dotacc = fmaf(fmaxf(vv[os][r], 0.f), w2v[r], dotacc);
        } else {
            f32x4 v = vv[os];
            if (EPI == 3) {
                const ushort4 rv = *(const ushort4*)(resid + (size_t)nr * O + ob);
                v[0] += bf2f(rv.x); v[1] += bf2f(rv.y); v[2] += bf2f(rv.z); v[3] += bf2f(rv.w);
            }
            if (EPI == 2) {
#pragma unroll
                for (int r = 0; r < 4; ++r) v[r] = fmaxf(v[r], 0.f);
            }
            ushort4 pk;
            pk.x = f2bf(v[0]); pk.y = f2bf(v[1]); pk.z = f2bf(v[2]); pk.w = f2bf(v[3]);
            *(ushort4*)((unsigned short*)Yv + (size_t)nr * O + ob) = pk;
        }
    }

    if (EPI == 5) {
        dotacc += __shfl_xor(dotacc, 16);
        dotacc += __shfl_xor(dotacc, 32);
        if (lg == 0) ((float*)Yv)[nr] = dotacc + ((const float*)parts)[0];
    }

    if (EPI == 0) {
        float* sred = (float*)ldsW;
        float s1[4][4], s2[4][4];
#pragma unroll
        for (int os = 0; os < 4; ++os)
#pragma unroll
            for (int r = 0; r < 4; ++r) {
                float a1 = vv[os][r], a2 = vv[os][r] * vv[os][r];
#pragma unroll
                for (int d = 1; d < 16; d <<= 1) {
                    a1 += __shfl_xor(a1, d);
                    a2 += __shfl_xor(a2, d);
                }
                s1[os][r] = a1; s2[os][r] = a2;
            }
        __syncthreads();
        if (lq == 0) {
#pragma unroll
            for (int os = 0; os < 4; ++os)
#pragma unroll
                for (int r = 0; r < 4; ++r) {
                    const int ch = os * 16 + lg * 4 + r;
                    sred[(w * 64 + ch) * 2 + 0] = s1[os][r];
                    sred[(w * 64 + ch) * 2 + 1] = s2[os][r];
                }
        }
        __syncthreads();
        if (tid < 128) {
            const int ch = tid & 63, st = tid >> 6;
            const float a = sred[ch * 2 + st] + sred[(64 + ch) * 2 + st]
                          + sred[(128 + ch) * 2 + st] + sred[(192 + ch) * 2 + st];
            parts[(size_t)st * O * 256 + (size_t)(o0 + ch) * 256 + blockIdx.x] = a;
        }
    }
}

// ---------------- fused QKV projection ----------------
__global__ __launch_bounds__(256) void qkv_kernel(const unsigned short* __restrict__ A,
                                                  const unsigned short* __restrict__ Wall,
                                                  const float* __restrict__ qb,
                                                  const float* __restrict__ kb,
                                                  const float* __restrict__ vb,
                                                  unsigned short* __restrict__ Qo,
                                                  unsigned short* __restrict__ Ko,
                                                  unsigned short* __restrict__ Vo) {
    constexpr int C = 256, RB = 512, SLOTS = 32;
    __shared__ __align__(16) char ldsW[64 * RB];
    const int tid = threadIdx.x;
    const int w = tid >> 6, l = tid & 63;
    const int lg = l >> 4, lq = l & 15;
    const int n0 = blockIdx.x * 64;
    const int by = blockIdx.y;
    const int proj = by >> 1;
    const int o0 = (by & 1) * 64;
    const unsigned short* Wb = Wall + (size_t)proj * 32768;
    const float* bias = (proj == 0) ? qb : (proj == 1) ? kb : vb;

#pragma unroll
    for (int i = 0; i < C / 32; ++i) {
        const int idx = i * 256 + tid;
        const int m  = idx / SLOTS;
        const int sl = (idx % SLOTS) ^ (m & 7);
        GLD_LDS16(Wb + (size_t)(o0 + m) * C + sl * 8, ldsW + (i * 256 + w * 64) * 16);
    }

    const int nr = n0 + w * 16 + lq;
    const unsigned short* Ap = A + (size_t)nr * C + lg * 8;
    f32x4 acc[4];
#pragma unroll
    for (int os = 0; os < 4; ++os) acc[os] = {0.f, 0.f, 0.f, 0.f};
    __syncthreads();

#pragma unroll
    for (int ks = 0; ks < C / 32; ++ks) {
        const bf16x8 af = *(const bf16x8*)(Ap + ks * 32);
#pragma unroll
        for (int os = 0; os < 4; ++os) {
            const int row = os * 16 + lq;
            const bf16x8 wf = *(const bf16x8*)(ldsW + ((row * RB + ks * 64 + lg * 16) ^ ((lq & 7) << 4)));
            acc[os] = __builtin_amdgcn_mfma_f32_16x16x32_bf16(wf, af, acc[os], 0, 0, 0);
        }
    }

#pragma unroll
    for (int os = 0; os < 4; ++os) {
        const int ob = o0 + os * 16 + lg * 4;
        const f32x4 bv = *(const f32x4*)(bias + ob);
        f32x4 v;
#pragma unroll
        for (int r = 0; r < 4; ++r) v[r] = acc[os][r] + bv[r];
        if (proj < 2) {
            unsigned short* Y = proj ? Ko : Qo;
            ushort4 pk;
            pk.x = f2bf(v[0]); pk.y = f2bf(v[1]); pk.z = f2bf(v[2]); pk.w = f2bf(v[3]);
            *(ushort4*)(Y + (size_t)nr * 128 + ob) = pk;
        } else {
            const int bb = nr >> 12, n = nr & (NPTS - 1);
#pragma unroll
            for (int r = 0; r < 4; ++r)
                Vo[((size_t)bb * HID + ob + r) * NPTS + n] = f2bf(v[r]);
        }
    }
}

// ---------------- fmha staging: one 32x128 K tile (8KB) + 128x32 V tile (8KB) ----------------
// K layout: [32 m][16 slot*16B] phys = lin ^ ((m&7)<<4)
// V layout: [128 h][4 slot*16B] phys = lin ^ ((h&3)<<4)
__device__ __forceinline__ void stage_tile(char* lds, int buf,
                                           const unsigned short* Kb,
                                           const unsigned short* Vb,
                                           int n0, int w, int l) {
    char* dK = lds + buf * 8192;
    char* dV = lds + 16384 + buf * 8192;
#pragma unroll
    for (int j = 0; j < 2; ++j) {
        const int y = j * 4096 + w * 1024 + l * 16;
        const int m = y >> 8;
        const int slot = ((y >> 4) & 15) ^ (m & 7);
        GLD_LDS16(Kb + (size_t)(n0 + m) * HID + slot * 8, dK + j * 4096 + w * 1024);
    }
#pragma unroll
    for (int j = 0; j < 2; ++j) {
        const int y = j * 4096 + w * 1024 + l * 16;
        const int h = y >> 6;
        const int slot = ((y >> 4) & 3) ^ (h & 3);
        GLD_LDS16(Vb + (size_t)h * NPTS + n0 + slot * 8, dV + j * 4096 + w * 1024);
    }
}

// ---------------- MFMA flash attention v3: KC=32, 36KB LDS (4 blocks/CU), cvt_pk ----------------
__global__ __launch_bounds__(256) void fmha2_kernel(const unsigned short* __restrict__ Qg,
                                                    const unsigned short* __restrict__ Kg,
                                                    const unsigned short* __restrict__ Vg,
                                                    float* __restrict__ A0, float* __restrict__ A1,
                                                    float* __restrict__ A2, float* __restrict__ A3,
                                                    float* __restrict__ Mb, float* __restrict__ Lb) {
    __shared__ __align__(16) char lds[36864];   // K dbuf 16K | V dbuf 16K | P 4x1K
    const int tid = threadIdx.x;
    const int w = tid >> 6, l = tid & 63;
    const int lg = l >> 4, lq = l & 15;
    const int b  = blockIdx.y;
    const int q0 = blockIdx.x * QR;
    const int split = blockIdx.z;
    const int n0base = split * (NPTS / NSPL);
    float* Ap = (split == 0) ? A0 : (split == 1) ? A1 : (split == 2) ? A2 : A3;
    float* Mp = Mb + split * NTOT;
    float* Lp = Lb + split * NTOT;
    char* ldsP = lds + 32768 + w * 1024;

    bf16x8 qf[4];
    {
        const unsigned short* qp = Qg + ((size_t)b * NPTS + q0 + w * 16 + lq) * HID + lg * 8;
#pragma unroll
        for (int ks = 0; ks < 4; ++ks)
            qf[ks] = *(const bf16x8*)(qp + ks * 32);
    }
    const unsigned short* Kb = Kg + (size_t)b * NPTS * HID;
    const unsigned short* Vb = Vg + (size_t)b * HID * NPTS;

    float m_r = -3.0e38f;
    float lsum = 0.f;
    f32x4 oacc[8];
#pragma unroll
    for (int hs = 0; hs < 8; ++hs) oacc[hs] = {0.f, 0.f, 0.f, 0.f};

    constexpr int NT = (NPTS / NSPL) / KC;   // 32 tiles
    stage_tile(lds, 0, Kb, Vb, n0base, w, l);

    for (int t = 0; t < NT; ++t) {
        const int cur = t & 1;
        __syncthreads();
        if (t + 1 < NT)
            stage_tile(lds, cur ^ 1, Kb, Vb, n0base + (t + 1) * KC, w, l);
        char* ldsK = lds + cur * 8192;
        char* ldsV = lds + 16384 + cur * 8192;

        // ---- QK^T: S[m][q], m = ms*16 + lg*4 + r (32 rows), q = lq ----
        f32x4 sv[2];
        __builtin_amdgcn_s_setprio(1);
#pragma unroll
        for (int ms = 0; ms < 2; ++ms) {
            const int row = ms * 16 + lq;
            f32x4 s = {0.f, 0.f, 0.f, 0.f};
#pragma unroll
            for (int ks = 0; ks < 4; ++ks) {
                bf16x8 kf = *(const bf16x8*)(ldsK + ((row * 256 + ks * 64 + lg * 16) ^ ((row & 7) << 4)));
                s = __builtin_amdgcn_mfma_f32_16x16x32_bf16(kf, qf[ks], s, 0, 0, 0);
            }
            sv[ms] = s;
        }
        __builtin_amdgcn_s_setprio(0);

        float pmax = fmaxf(fmaxf(fmaxf(sv[0][0], sv[0][1]), fmaxf(sv[0][2], sv[0][3])),
                           fmaxf(fmaxf(sv[1][0], sv[1][1]), fmaxf(sv[1][2], sv[1][3])));
        pmax = fmaxf(pmax, __shfl_xor(pmax, 16));
        pmax = fmaxf(pmax, __shfl_xor(pmax, 32));

        if (__any(pmax > m_r + 8.0f)) {
            const float newm = fmaxf(m_r, pmax);
            const float sc = __expf(m_r - newm);
            lsum *= sc;
            float sc_r[4];
#pragma unroll
            for (int r = 0; r < 4; ++r) sc_r[r] = __shfl(sc, lg * 4 + r);
#pragma unroll
            for (int hs = 0; hs < 8; ++hs)
#pragma unroll
                for (int r = 0; r < 4; ++r) oacc[hs][r] *= sc_r[r];
            m_r = newm;
        }

        // ---- exp + P -> LDS via v_cvt_pk_bf16_f32 ----
#pragma unroll
        for (int ms = 0; ms < 2; ++ms) {
            const float p0 = __expf(sv[ms][0] - m_r);
            const float p1 = __expf(sv[ms][1] - m_r);
            const float p2 = __expf(sv[ms][2] - m_r);
            const float p3 = __expf(sv[ms][3] - m_r);
            lsum += (p0 + p1) + (p2 + p3);
            uint2 pk;
            pk.x = cvtpk(p0, p1);
            pk.y = cvtpk(p2, p3);
            const int lin = lq * 64 + ms * 32 + lg * 8;
            *(uint2*)(ldsP + (lin ^ ((lq & 3) << 4))) = pk;
        }

        // ---- PV: single k=32 step ----
        __builtin_amdgcn_s_setprio(1);
        {
            bf16x8 pf = *(const bf16x8*)(ldsP + ((lq * 64 + lg * 16) ^ ((lq & 3) << 4)));
#pragma unroll
            for (int hs = 0; hs < 8; ++hs) {
                const int hrow = hs * 16 + lq;
                bf16x8 vf = *(const bf16x8*)(ldsV + ((hrow * 64 + lg * 16) ^ ((hrow & 3) << 4)));
                oacc[hs] = __builtin_amdgcn_mfma_f32_16x16x32_bf16(pf, vf, oacc[hs], 0, 0, 0);
            }
        }
        __builtin_amdgcn_s_setprio(0);
    }

    lsum += __shfl_xor(lsum, 16);
    lsum += __shfl_xor(lsum, 32);
    float* Ab = Ap + ((size_t)b * NPTS + q0 + w * 16) * HID;
#pragma unroll
    for (int hs = 0; hs < 8; ++hs) {
#pragma unroll
        for (int r = 0; r < 4; ++r)
            Ab[(size_t)(lg * 4 + r) * HID + hs * 16 + lq] = oacc[hs][r];
    }
    if (lg == 0) {
        Mp[b * NPTS + q0 + w * 16 + lq] = m_r;
        Lp[b * NPTS + q0 + w * 16 + lq] = lsum;
    }
}

// ---------------- combine 4 splits -> bf16 [nr][128] ----------------
__global__ __launch_bounds__(256) void fmha_combine_kernel(const float* __restrict__ A0,
                                                           const float* __restrict__ A1,
                                                           const float* __restrict__ A2,
                                                           const float* __restrict__ A3,
                                                           const float* __restrict__ Mb,
                                                           const float* __restrict__ Lb,
                                                           unsigned short* __restrict__ Ob) {
    const int i = blockIdx.x * 256 + threadIdx.x;
    const int nidx = i >> 7;
    const float m0 = Mb[nidx], m1 = Mb[NTOT + nidx];
    const float m2 = Mb[2 * NTOT + nidx], m3 = Mb[3 * NTOT + nidx];
    const float M = fmaxf(fmaxf(m0, m1), fmaxf(m2, m3));
    const float e0 = __expf(m0 - M), e1 = __expf(m1 - M);
    const float e2 = __expf(m2 - M), e3 = __expf(m3 - M);
    const float den = e0 * Lb[nidx] + e1 * Lb[NTOT + nidx]
                    + e2 * Lb[2 * NTOT + nidx] + e3 * Lb[3 * NTOT + nidx];
    const float num = e0 * A0[i] + e1 * A1[i] + e2 * A2[i] + e3 * A3[i];
    Ob[i] = f2bf(num / den);
}

// ---------------- softmax over N of pooling scores ----------------
__global__ __launch_bounds__(256) void softmax_w_kernel(float* __restrict__ s) {
    const int b = blockIdx.x;
    const int tid = threadIdx.x;
    __shared__ float red[256];
    float lm = -3.0e38f;
    for (int n = tid; n < NPTS; n += 256) lm = fmaxf(lm, s[b * NPTS + n]);
    red[tid] = lm;
    __syncthreads();
    for (int st = 128; st > 0; st >>= 1) {
        if (tid < st) red[tid] = fmaxf(red[tid], red[tid + st]);
        __syncthreads();
    }
    const float mx = red[0];
    __syncthreads();
    float ls = 0.f;
    for (int n = tid; n < NPTS; n += 256) {
        const float p = __expf(s[b * NPTS + n] - mx);
        s[b * NPTS + n] = p;
        ls += p;
    }
    red[tid] = ls;
    __syncthreads();
    for (int st = 128; st > 0; st >>= 1) {
        if (tid < st) red[tid] += red[tid + st];
        __syncthreads();
    }
    const float inv = 1.f / red[0];
    __syncthreads();
    for (int n = tid; n < NPTS; n += 256) s[b * NPTS + n] *= inv;
}

// ---------------- weighted pooling ----------------
__global__ __launch_bounds__(256) void pool3_kernel(const unsigned short* __restrict__ h,
                                                    const float* __restrict__ w,
                                                    float* __restrict__ pooled) {
    const int b  = blockIdx.y;
    const int n0 = blockIdx.x * 64;
    const int cg = (threadIdx.x & 63) * 4;
    const int rs = threadIdx.x >> 6;
    float a0 = 0.f, a1 = 0.f, a2 = 0.f, a3 = 0.f;
#pragma unroll 4
    for (int i = 0; i < 16; ++i) {
        const int n = n0 + i * 4 + rs;
        const ushort4 v = *(const ushort4*)(h + ((size_t)b * NPTS + n) * 256 + cg);
        const float wv = w[b * NPTS + n];
        a0 = fmaf(bf2f(v.x), wv, a0);
        a1 = fmaf(bf2f(v.y), wv, a1);
        a2 = fmaf(bf2f(v.z), wv, a2);
        a3 = fmaf(bf2f(v.w), wv, a3);
    }
    float* pp = pooled + b * 256 + cg;
    atomicAdd(pp + 0, a0);
    atomicAdd(pp + 1, a1);
    atomicAdd(pp + 2, a2);
    atomicAdd(pp + 3, a3);
}

// ---------------- final FC + ReLU ----------------
__global__ __launch_bounds__(256) void fc_kernel(const float* __restrict__ pooled,
                                                 const float* __restrict__ fcw,
                                                 const float* __restrict__ fcb,
                                                 float* __restrict__ out) {
    const int b = blockIdx.x, j = threadIdx.x;
    __shared__ float ps[256];
    ps[j] = pooled[b * 256 + j];
    __syncthreads();
    float acc = fcb[j];
    for (int c = 0; c < 256; ++c) acc = fmaf(ps[c], fcw[j * 256 + c], acc);
    out[b * 256 + j] = fmaxf(acc, 0.f);
}

extern "C" void kernel_launch(void* const* d_in, const int* in_sizes, int n_in,
                              void* d_out, int out_size, void* d_ws, size_t ws_size,
                              hipStream_t stream) {
    const float* x   = (const float*)d_in[0];
    const float* w1  = (const float*)d_in[1];
    const float* b1  = (const float*)d_in[2];
    const float* g1  = (const float*)d_in[3];
    const float* be1 = (const float*)d_in[4];
    const float* w2  = (const float*)d_in[5];
    const float* b2  = (const float*)d_in[6];
    const float* g2  = (const float*)d_in[7];
    const float* be2 = (const float*)d_in[8];
    const float* w3  = (const float*)d_in[9];
    const float* b3  = (const float*)d_in[10];
    const float* g3  = (const float*)d_in[11];
    const float* be3 = (const float*)d_in[12];
    const float* qw  = (const float*)d_in[13];
    const float* qb  = (const float*)d_in[14];
    const float* kw  = (const float*)d_in[15];
    const float* kb  = (const float*)d_in[16];
    const float* vw  = (const float*)d_in[17];
    const float* vb  = (const float*)d_in[18];
    const float* fw  = (const float*)d_in[19];
    const float* fb  = (const float*)d_in[20];
    const float* aw1 = (const float*)d_in[21];
    const float* ab1 = (const float*)d_in[22];
    const float* aw2 = (const float*)d_in[23];
    const float* ab2 = (const float*)d_in[24];
    const float* fcw = (const float*)d_in[25];
    const float* fcb = (const float*)d_in[26];

    // ---- workspace layout (f32 units), lifetime-checked arenas ----
    float* ws = (float*)d_ws;
    float* h0     = ws;
    float* arena1 = h0 + 294912;           // y1/y2/y3 -> Acc2|Acc3
    float* arena2 = arena1 + 4194304;      // h3b
    float* arena3 = arena2 + 2097152;      // h1b -> h2b -> Qb -> OBF
    float* arena4 = arena3 + 1048576;      // Kb
    float* arena5 = arena4 + 1048576;      // Vb
    float* arena6 = arena5 + 1048576;      // Acc0 -> h4b
    float* arena7 = arena6 + 2097152;      // Acc1
    float* Mls    = arena7 + 2097152;      // M[4][NTOT] | L[4][NTOT]
    float* s      = Mls + 131072;
    float* pooled = s + 16384;
    float* mstats = pooled + 1024;
    float* wbf    = mstats + 512;
    float* xyzwp  = wbf + 94208;
    float* parts  = xyzwp + 65536;

    float* y1 = arena1;
    float* y2 = arena1;
    float* y3 = arena1;
    unsigned short* H1b = (unsigned short*)arena3;
    unsigned short* H2b = (unsigned short*)arena3;
    unsigned short* Qb  = (unsigned short*)arena3;
    unsigned short* OBF = (unsigned short*)arena3;
    unsigned short* H3b = (unsigned short*)arena2;
    unsigned short* Kb  = (unsigned short*)arena4;
    unsigned short* Vb  = (unsigned short*)arena5;
    float* Acc0 = arena6;
    unsigned short* H4b = (unsigned short*)arena6;
    float* Acc1 = arena7;
    float* Acc2 = arena1;
    float* Acc3 = arena1 + 2097152;
    float* Mb = Mls;
    float* Lb = Mls + 4 * NTOT;
    unsigned short* WB = (unsigned short*)wbf;
    unsigned short* w2b  = WB;
    unsigned short* w3b  = WB + 8192;
    unsigned short* qwb  = WB + 40960;
    unsigned short* fwb  = WB + 139264;
    unsigned short* aw1b = WB + 172032;
    float4* xyzw = (float4*)xyzwp;

    hipMemsetAsync(pooled, 0, 1024 * sizeof(float), stream);
    prep_kernel<<<dim3(736), 256, 0, stream>>>(x, xyzw, w2, w3, qw, kw, vw, fw, aw1, WB);
    knn3_kernel<<<dim3(NTOT / 8), 256, 0, stream>>>(x, xyzw, h0);

    conv1_kernel<<<dim3(NPTS / 64, 4, B), 256, 0, stream>>>(h0, w1, b1, y1, parts);
    finstats_kernel<<<64, 64, 0, stream>>>(parts, mstats, 64);
    bnapply_kernel<<<dim3(NTOT * 64 / 1024), 256, 0, stream>>>(y1, mstats, g1, be1, H1b, 64);
    gemm_kernel<64, 0><<<dim3(NTOT / 64, 2), 256, 0, stream>>>(H1b, w2b, b2, nullptr, y2, 128, parts);
    finstats_kernel<<<128, 64, 0, stream>>>(parts, mstats, 128);
    bnapply_kernel<<<dim3(NTOT * 128 / 1024), 256, 0, stream>>>(y2, mstats, g2, be2, H2b, 128);
    gemm_kernel<128, 0><<<dim3(NTOT / 64, 4), 256, 0, stream>>>(H2b, w3b, b3, nullptr, y3, 256, parts);
    finstats_kernel<<<256, 64, 0, stream>>>(parts, mstats, 256);
    bnapply_kernel<<<dim3(NTOT * 256 / 1024), 256, 0, stream>>>(y3, mstats, g3, be3, H3b, 256);

    qkv_kernel<<<dim3(NTOT / 64, 6), 256, 0, stream>>>(H3b, qwb, qb, kb, vb, Qb, Kb, Vb);

    fmha2_kernel<<<dim3(NPTS / QR, B, NSPL), 256, 0, stream>>>(Qb, Kb, Vb, Acc0, Acc1, Acc2, Acc3, Mb, Lb);
    fmha_combine_kernel<<<dim3(NTOT * HID / 256), 256, 0, stream>>>(Acc0, Acc1, Acc2, Acc3, Mb, Lb, OBF);

    gemm_kernel<128, 3><<<dim3(NTOT / 64, 4), 256, 0, stream>>>(OBF, fwb, fb, H3b, H4b, 256, nullptr);
    gemm_kernel<256, 5><<<dim3(NTOT / 64, 1), 256, 0, stream>>>(H4b, aw1b, ab1,
                                                                (const unsigned short*)aw2, s, 64, (float*)ab2);

    softmax_w_kernel<<<B, 256, 0, stream>>>(s);
    pool3_kernel<<<dim3(64, B), 256, 0, stream>>>(H4b, s, pooled);
    fc_kernel<<<B, 256, 0, stream>>>(pooled, fcw, fcb, (float*)d_out);

    (void)in_sizes; (void)n_in; (void)out_size; (void)ws_size;
}

// Round 16
// 244.894 us; speedup vs baseline: 1.0510x; 1.0510x over previous
//
#include <hip/hip_runtime.h>
#include <math.h>

constexpr int B    = 4;
constexpr int NPTS = 4096;
constexpr int NTOT = B * NPTS;
constexpr int CIN  = 9;
constexpr int C0   = 18;
constexpr int KNB  = 8;
constexpr int HID  = 128;
constexpr int QR   = 64;    // q rows per fmha block
constexpr int KC   = 64;    // m per fmha tile
constexpr int NSPL = 4;     // fmha KV splits
constexpr float EPSF = 1e-5f;

using f32x4  = __attribute__((ext_vector_type(4))) float;
using bf16x8 = __attribute__((ext_vector_type(8))) short;

__device__ inline unsigned short f2bf(float f) {
    unsigned int x = __float_as_uint(f);
    unsigned int r = (x + 0x7fffu + ((x >> 16) & 1u)) >> 16;
    return (unsigned short)r;
}
__device__ inline float bf2f(unsigned short u) {
    return __uint_as_float(((unsigned int)u) << 16);
}
// HW packed f32->bf16 (RNE), validated round 13
__device__ inline unsigned int cvtpk(float lo, float hi) {
    unsigned int r;
    asm("v_cvt_pk_bf16_f32 %0, %1, %2" : "=v"(r) : "v"(lo), "v"(hi));
    return r;
}

#define GLD_LDS16(g, l) __builtin_amdgcn_global_load_lds( \
    (const __attribute__((address_space(1))) void*)(g),   \
    (__attribute__((address_space(3))) void*)(l), 16, 0, 0)

// ---------------- prep: weight pack f32->bf16 (7 segments) + xyz pack ----------------
__global__ __launch_bounds__(256) void prep_kernel(const float* __restrict__ x,
                                                   float4* __restrict__ xyzw,
                                                   const float* __restrict__ w2,
                                                   const float* __restrict__ w3,
                                                   const float* __restrict__ qw,
                                                   const float* __restrict__ kw,
                                                   const float* __restrict__ vw,
                                                   const float* __restrict__ fw,
                                                   const float* __restrict__ aw1,
                                                   unsigned short* __restrict__ dst) {
    const int i = blockIdx.x * 256 + threadIdx.x;   // 188416 total
    if (i < NTOT) {
        const float* xp = x + (size_t)i * CIN;
        const float a = xp[0], b = xp[1], c = xp[2];
        xyzw[i] = make_float4(a, b, c, a * a + b * b + c * c);
    }
    const float* src;
    int off;
    if      (i <   8192) { src = w2;  off = 0; }
    else if (i <  40960) { src = w3;  off = 8192; }
    else if (i <  73728) { src = qw;  off = 40960; }
    else if (i < 106496) { src = kw;  off = 73728; }
    else if (i < 139264) { src = vw;  off = 106496; }
    else if (i < 172032) { src = fw;  off = 139264; }
    else                 { src = aw1; off = 172032; }
    dst[i] = f2bf(src[i - off]);
}

// ---------------- KNN v5: packed u32 (dist20|idx12) keys ----------------
__global__ __launch_bounds__(256) void knn3_kernel(const float* __restrict__ x,
                                                   const float4* __restrict__ xyzw,
                                                   float* __restrict__ h0) {
    __shared__ __align__(16) char lds[16384];
    const int tid = threadIdx.x;
    const int w = tid >> 6, l = tid & 63;
    const int b  = blockIdx.x >> 9;
    const int p0 = (blockIdx.x & 511) << 3;
    const int c  = l & 31;
    const int n  = p0 + w * 2 + (l >> 5);
    const float4* xb4 = xyzw + (size_t)b * NPTS;

    const float4 q4 = xb4[n];
    const float qx = q4.x, qy = q4.y, qz = q4.z, sqn = q4.w;

    unsigned int bd[KNB];
#pragma unroll
    for (int i = 0; i < KNB; ++i) bd[i] = 0xFFFFFFFFu;

    auto stage = [&](int buf, int t) {
#pragma unroll
        for (int i = 0; i < 2; ++i) {
            const int idx = i * 256 + w * 64 + l;
            const int m   = idx ^ ((idx >> 4) & 7);
            GLD_LDS16(xb4 + (size_t)t * 512 + m, lds + buf * 8192 + i * 4096 + w * 1024);
        }
    };

    stage(0, 0);
    for (int t = 0; t < 8; ++t) {
        const int cur = t & 1;
        __syncthreads();
        if (t < 7) stage(cur ^ 1, t + 1);

        const char* buf = lds + cur * 8192 + c * 256;
        const int mbase = t * 512 + c * 16;
        const int cswz  = (c & 7) << 4;
#pragma unroll 4
        for (int j = 0; j < 16; ++j) {
            const float4 f4 = *(const float4*)(buf + ((j << 4) ^ cswz));
            const float tt = fmaf(qx, f4.x, fmaf(qy, f4.y, qz * f4.z));
            const float d2 = fmaxf(fmaf(-2.0f, tt, sqn + f4.w), 0.f);
            const int m = mbase + j;
            unsigned int key = (__float_as_uint(d2) & 0xFFFFF000u) | (unsigned int)m;
            if (m == n) key = 0xFFFFFFFFu;
            bd[KNB - 1] = min(bd[KNB - 1], key);
#pragma unroll
            for (int s = KNB - 1; s > 0; --s) {
                const unsigned int lo = min(bd[s - 1], bd[s]);
                const unsigned int hi = max(bd[s - 1], bd[s]);
                bd[s - 1] = lo; bd[s] = hi;
            }
        }
    }

    unsigned int res[KNB];
#pragma unroll
    for (int r = 0; r < KNB; ++r) {
        unsigned int v = bd[0];
#pragma unroll
        for (int mask = 16; mask > 0; mask >>= 1)
            v = min(v, (unsigned int)__shfl_xor((int)v, mask));
        res[r] = v;
        if (bd[0] == v) {
#pragma unroll
            for (int s = 0; s < KNB - 1; ++s) bd[s] = bd[s + 1];
            bd[KNB - 1] = 0xFFFFFFFFu;
        }
    }

    const int c8 = c & 7;
    unsigned int kk = res[0];
#pragma unroll
    for (int k = 1; k < KNB; ++k) kk = (c8 == k) ? res[k] : kk;
    const int nb = (int)(kk & 0xFFFu);
    const float* xb = x + (size_t)b * NPTS * CIN;
    float nv[CIN];
    const float* nbp = xb + (size_t)nb * CIN;
#pragma unroll
    for (int ch = 0; ch < CIN; ++ch) nv[ch] = nbp[ch];
#pragma unroll
    for (int d = 1; d < 8; d <<= 1) {
#pragma unroll
        for (int ch = 0; ch < CIN; ++ch) nv[ch] += __shfl_xor(nv[ch], d);
    }
    const int ch = min(c, 8);
    float nvc = nv[0];
#pragma unroll
    for (int k = 1; k < CIN; ++k) nvc = (ch == k) ? nv[k] : nvc;
    if (c < 9) {
        const float xv = xb[(size_t)n * CIN + ch];
        h0[((size_t)b * C0 + ch) * NPTS + n]       = nvc * 0.125f - xv;
        h0[((size_t)b * C0 + CIN + ch) * NPTS + n] = xv;
    }
}

// ---------------- layer-1 conv (fp32, C=18) + partial stats ----------------
__global__ __launch_bounds__(256) void conv1_kernel(const float* __restrict__ X,
                                                    const float* __restrict__ W,
                                                    const float* __restrict__ bias,
                                                    float* __restrict__ Y,
                                                    float* __restrict__ parts) {
    __shared__ float Ws[16 * C0];
    const int b  = blockIdx.z;
    const int o_base = blockIdx.y * 16;
    const int l  = threadIdx.x & 63;
    const int n  = blockIdx.x * 64 + l;
    const int og = threadIdx.x >> 6;
    for (int i = threadIdx.x; i < 16 * C0; i += 256)
        Ws[i] = W[(size_t)o_base * C0 + i];
    __syncthreads();
    float acc[4] = {0.f, 0.f, 0.f, 0.f};
    const float* Xp = X + (size_t)b * C0 * NPTS + n;
    for (int c = 0; c < C0; ++c) {
        const float xv = Xp[(size_t)c * NPTS];
#pragma unroll
        for (int i = 0; i < 4; ++i)
            acc[i] = fmaf(Ws[(og * 4 + i) * C0 + c], xv, acc[i]);
    }
    f32x4 v;
#pragma unroll
    for (int i = 0; i < 4; ++i) v[i] = acc[i] + bias[o_base + og * 4 + i];
    *(f32x4*)(Y + ((size_t)b * NPTS + n) * 64 + o_base + og * 4) = v;
    float s1[4], s2[4];
#pragma unroll
    for (int i = 0; i < 4; ++i) { s1[i] = v[i]; s2[i] = v[i] * v[i]; }
#pragma unroll
    for (int d = 1; d < 64; d <<= 1) {
#pragma unroll
        for (int i = 0; i < 4; ++i) {
            s1[i] += __shfl_xor(s1[i], d);
            s2[i] += __shfl_xor(s2[i], d);
        }
    }
    if (l == 0) {
        const int rg = blockIdx.z * 64 + blockIdx.x;
#pragma unroll
        for (int i = 0; i < 4; ++i) {
            const int ch = o_base + og * 4 + i;
            parts[ch * 256 + rg]            = s1[i];
            parts[64 * 256 + ch * 256 + rg] = s2[i];
        }
    }
}

// ---------------- finalize stats ----------------
__global__ __launch_bounds__(64) void finstats_kernel(const float* __restrict__ parts,
                                                      float* __restrict__ mstats, int O) {
    const int ch = blockIdx.x, l = threadIdx.x;
    const f32x4 a1 = *(const f32x4*)(parts + (size_t)ch * 256 + l * 4);
    const f32x4 a2 = *(const f32x4*)(parts + (size_t)O * 256 + (size_t)ch * 256 + l * 4);
    float s1 = (a1[0] + a1[1]) + (a1[2] + a1[3]);
    float s2 = (a2[0] + a2[1]) + (a2[2] + a2[3]);
#pragma unroll
    for (int d = 1; d < 64; d <<= 1) {
        s1 += __shfl_xor(s1, d);
        s2 += __shfl_xor(s2, d);
    }
    if (l == 0) {
        const float mean = s1 * (1.0f / NTOT);
        const float var  = s2 * (1.0f / NTOT) - mean * mean;
        mstats[ch]     = mean;
        mstats[O + ch] = rsqrtf(var + EPSF);
    }
}

// ---------------- BN apply + ReLU -> bf16 ----------------
__global__ __launch_bounds__(256) void bnapply_kernel(const float* __restrict__ Y,
                                                      const float* __restrict__ mstats,
                                                      const float* __restrict__ g,
                                                      const float* __restrict__ be,
                                                      unsigned short* __restrict__ Yb,
                                                      int O) {
    const size_t i4 = (size_t)blockIdx.x * 256 + threadIdx.x;
    const int cbase = (int)((i4 * 4) & (O - 1));
    const f32x4 v = *(const f32x4*)(Y + i4 * 4);
    ushort4 pk;
    unsigned short* pp = (unsigned short*)&pk;
#pragma unroll
    for (int r = 0; r < 4; ++r) {
        const int c = cbase + r;
        const float y = fmaxf(g[c] * mstats[O + c] * (v[r] - mstats[c]) + be[c], 0.f);
        pp[r] = f2bf(y);
    }
    *(ushort4*)(Yb + i4 * 4) = pk;
}

// ---------------- bf16 MFMA GEMM ----------------
// EPI: 0 = f32 out + partial-stats stores; 1 = bf16 bias; 2 = bf16 bias+relu;
//      3 = bf16 bias+residual; 4 = V-transpose bf16 bias;
//      5 = relu + fused aw2 dot -> s[nr] (resid carries aw2, parts carries ab2)
template <int C, int EPI>
__global__ __launch_bounds__(256) void gemm_kernel(const unsigned short* __restrict__ A,
                                                   const unsigned short* __restrict__ Wb,
                                                   const float* __restrict__ bias,
                                                   const unsigned short* __restrict__ resid,
                                                   void* __restrict__ Yv, int O,
                                                   float* __restrict__ parts) {
    constexpr int RB = 2 * C;
    constexpr int SLOTS = C / 8;
    __shared__ __align__(16) char ldsW[64 * RB];
    const int tid = threadIdx.x;
    const int w = tid >> 6, l = tid & 63;
    const int lg = l >> 4, lq = l & 15;
    const int n0 = blockIdx.x * 64;
    const int o0 = blockIdx.y * 64;

#pragma unroll
    for (int i = 0; i < C / 32; ++i) {
        const int idx = i * 256 + tid;
        const int m  = idx / SLOTS;
        const int sl = (idx % SLOTS) ^ (m & 7);
        GLD_LDS16(Wb + (size_t)(o0 + m) * C + sl * 8, ldsW + (i * 256 + w * 64) * 16);
    }

    const int nr = n0 + w * 16 + lq;
    const unsigned short* Ap = A + (size_t)nr * C + lg * 8;
    f32x4 acc[4];
#pragma unroll
    for (int os = 0; os < 4; ++os) acc[os] = {0.f, 0.f, 0.f, 0.f};
    __syncthreads();

#pragma unroll
    for (int ks = 0; ks < C / 32; ++ks) {
        const bf16x8 af = *(const bf16x8*)(Ap + ks * 32);
#pragma unroll
        for (int os = 0; os < 4; ++os) {
            const int row = os * 16 + lq;
            const bf16x8 wf = *(const bf16x8*)(ldsW + ((row * RB + ks * 64 + lg * 16) ^ ((lq & 7) << 4)));
            acc[os] = __builtin_amdgcn_mfma_f32_16x16x32_bf16(wf, af, acc[os], 0, 0, 0);
        }
    }

    f32x4 vv[4];
    float dotacc = 0.f;
#pragma unroll
    for (int os = 0; os < 4; ++os) {
        const int ob = o0 + os * 16 + lg * 4;
        const f32x4 bv = *(const f32x4*)(bias + ob);
#pragma unroll
        for (int r = 0; r < 4; ++r) vv[os][r] = acc[os][r] + bv[r];
        if (EPI == 0) {
            *(f32x4*)((float*)Yv + (size_t)nr * O + ob) = vv[os];
        } else if (EPI == 4) {
            unsigned short* Y = (unsigned short*)Yv;
            const int bb = nr >> 12, n = nr & (NPTS - 1);
#pragma unroll
            for (int r = 0; r < 4; ++r)
                Y[((size_t)bb * HID + ob + r) * NPTS + n] = f2bf(vv[os][r]);
        } else if (EPI == 5) {
            const f32x4 w2v = *(const f32x4*)((const float*)resid + ob);
#pragma unroll
            for (int r = 0; r < 4; ++r)
                dotacc = fmaf(fmaxf(vv[os][r], 0.f), w2v[r], dotacc);
        } else {
            f32x4 v = vv[os];
            if (EPI == 3) {
                const ushort4 rv = *(const ushort4*)(resid + (size_t)nr * O + ob);
                v[0] += bf2f(rv.x); v[1] += bf2f(rv.y); v[2] += bf2f(rv.z); v[3] += bf2f(rv.w);
            }
            if (EPI == 2) {
#pragma unroll
                for (int r = 0; r < 4; ++r) v[r] = fmaxf(v[r], 0.f);
            }
            ushort4 pk;
            pk.x = f2bf(v[0]); pk.y = f2bf(v[1]); pk.z = f2bf(v[2]); pk.w = f2bf(v[3]);
            *(ushort4*)((unsigned short*)Yv + (size_t)nr * O + ob) = pk;
        }
    }

    if (EPI == 5) {
        dotacc += __shfl_xor(dotacc, 16);
        dotacc += __shfl_xor(dotacc, 32);
        if (lg == 0) ((float*)Yv)[nr] = dotacc + ((const float*)parts)[0];
    }

    if (EPI == 0) {
        float* sred = (float*)ldsW;
        float s1[4][4], s2[4][4];
#pragma unroll
        for (int os = 0; os < 4; ++os)
#pragma unroll
            for (int r = 0; r < 4; ++r) {
                float a1 = vv[os][r], a2 = vv[os][r] * vv[os][r];
#pragma unroll
                for (int d = 1; d < 16; d <<= 1) {
                    a1 += __shfl_xor(a1, d);
                    a2 += __shfl_xor(a2, d);
                }
                s1[os][r] = a1; s2[os][r] = a2;
            }
        __syncthreads();
        if (lq == 0) {
#pragma unroll
            for (int os = 0; os < 4; ++os)
#pragma unroll
                for (int r = 0; r < 4; ++r) {
                    const int ch = os * 16 + lg * 4 + r;
                    sred[(w * 64 + ch) * 2 + 0] = s1[os][r];
                    sred[(w * 64 + ch) * 2 + 1] = s2[os][r];
                }
        }
        __syncthreads();
        if (tid < 128) {
            const int ch = tid & 63, st = tid >> 6;
            const float a = sred[ch * 2 + st] + sred[(64 + ch) * 2 + st]
                          + sred[(128 + ch) * 2 + st] + sred[(192 + ch) * 2 + st];
            parts[(size_t)st * O * 256 + (size_t)(o0 + ch) * 256 + blockIdx.x] = a;
        }
    }
}

// ---------------- fused QKV projection ----------------
__global__ __launch_bounds__(256) void qkv_kernel(const unsigned short* __restrict__ A,
                                                  const unsigned short* __restrict__ Wall,
                                                  const float* __restrict__ qb,
                                                  const float* __restrict__ kb,
                                                  const float* __restrict__ vb,
                                                  unsigned short* __restrict__ Qo,
                                                  unsigned short* __restrict__ Ko,
                                                  unsigned short* __restrict__ Vo) {
    constexpr int C = 256, RB = 512, SLOTS = 32;
    __shared__ __align__(16) char ldsW[64 * RB];
    const int tid = threadIdx.x;
    const int w = tid >> 6, l = tid & 63;
    const int lg = l >> 4, lq = l & 15;
    const int n0 = blockIdx.x * 64;
    const int by = blockIdx.y;
    const int proj = by >> 1;
    const int o0 = (by & 1) * 64;
    const unsigned short* Wb = Wall + (size_t)proj * 32768;
    const float* bias = (proj == 0) ? qb : (proj == 1) ? kb : vb;

#pragma unroll
    for (int i = 0; i < C / 32; ++i) {
        const int idx = i * 256 + tid;
        const int m  = idx / SLOTS;
        const int sl = (idx % SLOTS) ^ (m & 7);
        GLD_LDS16(Wb + (size_t)(o0 + m) * C + sl * 8, ldsW + (i * 256 + w * 64) * 16);
    }

    const int nr = n0 + w * 16 + lq;
    const unsigned short* Ap = A + (size_t)nr * C + lg * 8;
    f32x4 acc[4];
#pragma unroll
    for (int os = 0; os < 4; ++os) acc[os] = {0.f, 0.f, 0.f, 0.f};
    __syncthreads();

#pragma unroll
    for (int ks = 0; ks < C / 32; ++ks) {
        const bf16x8 af = *(const bf16x8*)(Ap + ks * 32);
#pragma unroll
        for (int os = 0; os < 4; ++os) {
            const int row = os * 16 + lq;
            const bf16x8 wf = *(const bf16x8*)(ldsW + ((row * RB + ks * 64 + lg * 16) ^ ((lq & 7) << 4)));
            acc[os] = __builtin_amdgcn_mfma_f32_16x16x32_bf16(wf, af, acc[os], 0, 0, 0);
        }
    }

#pragma unroll
    for (int os = 0; os < 4; ++os) {
        const int ob = o0 + os * 16 + lg * 4;
        const f32x4 bv = *(const f32x4*)(bias + ob);
        f32x4 v;
#pragma unroll
        for (int r = 0; r < 4; ++r) v[r] = acc[os][r] + bv[r];
        if (proj < 2) {
            unsigned short* Y = proj ? Ko : Qo;
            ushort4 pk;
            pk.x = f2bf(v[0]); pk.y = f2bf(v[1]); pk.z = f2bf(v[2]); pk.w = f2bf(v[3]);
            *(ushort4*)(Y + (size_t)nr * 128 + ob) = pk;
        } else {
            const int bb = nr >> 12, n = nr & (NPTS - 1);
#pragma unroll
            for (int r = 0; r < 4; ++r)
                Vo[((size_t)bb * HID + ob + r) * NPTS + n] = f2bf(v[r]);
        }
    }
}

// ---------------- fmha staging: 64x128 K tile + 128x64 V tile (16KB each) ----------------
__device__ __forceinline__ void stage_tile(char* lds, int buf,
                                           const unsigned short* Kb,
                                           const unsigned short* Vb,
                                           int n0, int w, int l) {
    char* dK = lds + buf * 16384;
    char* dV = lds + 32768 + buf * 16384;
#pragma unroll
    for (int j = 0; j < 4; ++j) {
        const int y = w * 4096 + j * 1024 + l * 16;
        const int m = y >> 8;
        const int slot = ((y >> 4) & 15) ^ (m & 7);
        GLD_LDS16(Kb + (size_t)(n0 + m) * HID + slot * 8, dK + w * 4096 + j * 1024);
    }
#pragma unroll
    for (int j = 0; j < 4; ++j) {
        const int y = w * 4096 + j * 1024 + l * 16;
        const int h = y >> 7;
        const int slot = ((y >> 4) & 7) ^ (h & 7);
        GLD_LDS16(Vb + (size_t)h * NPTS + n0 + slot * 8, dV + w * 4096 + j * 1024);
    }
}

// ---------------- MFMA flash attention (round-12 proven structure), KV-split x4 ----------------
__global__ __launch_bounds__(256) void fmha2_kernel(const unsigned short* __restrict__ Qg,
                                                    const unsigned short* __restrict__ Kg,
                                                    const unsigned short* __restrict__ Vg,
                                                    float* __restrict__ A0, float* __restrict__ A1,
                                                    float* __restrict__ A2, float* __restrict__ A3,
                                                    float* __restrict__ Mb, float* __restrict__ Lb) {
    __shared__ __align__(16) char lds[73728];   // K dbuf 32K | V dbuf 32K | P 4x2K
    const int tid = threadIdx.x;
    const int w = tid >> 6, l = tid & 63;
    const int lg = l >> 4, lq = l & 15;
    const int b  = blockIdx.y;
    const int q0 = blockIdx.x * QR;
    const int split = blockIdx.z;
    const int n0base = split * (NPTS / NSPL);
    float* Ap = (split == 0) ? A0 : (split == 1) ? A1 : (split == 2) ? A2 : A3;
    float* Mp = Mb + split * NTOT;
    float* Lp = Lb + split * NTOT;
    char* ldsP = lds + 65536 + w * 2048;

    bf16x8 qf[4];
    {
        const unsigned short* qp = Qg + ((size_t)b * NPTS + q0 + w * 16 + lq) * HID + lg * 8;
#pragma unroll
        for (int ks = 0; ks < 4; ++ks)
            qf[ks] = *(const bf16x8*)(qp + ks * 32);
    }
    const unsigned short* Kb = Kg + (size_t)b * NPTS * HID;
    const unsigned short* Vb = Vg + (size_t)b * HID * NPTS;

    float m_r = -3.0e38f;
    float lsum = 0.f;
    f32x4 oacc[8];
#pragma unroll
    for (int hs = 0; hs < 8; ++hs) oacc[hs] = {0.f, 0.f, 0.f, 0.f};

    constexpr int NT = (NPTS / NSPL) / KC;
    stage_tile(lds, 0, Kb, Vb, n0base, w, l);

    for (int t = 0; t < NT; ++t) {
        const int cur = t & 1;
        __syncthreads();
        if (t + 1 < NT)
            stage_tile(lds, cur ^ 1, Kb, Vb, n0base + (t + 1) * KC, w, l);
        char* ldsK = lds + cur * 16384;
        char* ldsV = lds + 32768 + cur * 16384;

        f32x4 sv[4];
        __builtin_amdgcn_s_setprio(1);
#pragma unroll
        for (int ms = 0; ms < 4; ++ms) {
            const int row = ms * 16 + lq;
            f32x4 s = {0.f, 0.f, 0.f, 0.f};
#pragma unroll
            for (int ks = 0; ks < 4; ++ks) {
                bf16x8 kf = *(const bf16x8*)(ldsK + ((row * 256 + ks * 64 + lg * 16) ^ ((row & 7) << 4)));
                s = __builtin_amdgcn_mfma_f32_16x16x32_bf16(kf, qf[ks], s, 0, 0, 0);
            }
            sv[ms] = s;
        }
        __builtin_amdgcn_s_setprio(0);

        float pmax = sv[0][0];
#pragma unroll
        for (int ms = 0; ms < 4; ++ms)
#pragma unroll
            for (int r = 0; r < 4; ++r) pmax = fmaxf(pmax, sv[ms][r]);
        pmax = fmaxf(pmax, __shfl_xor(pmax, 16));
        pmax = fmaxf(pmax, __shfl_xor(pmax, 32));

        if (__any(pmax > m_r + 8.0f)) {
            const float newm = fmaxf(m_r, pmax);
            const float sc = __expf(m_r - newm);
            lsum *= sc;
            float sc_r[4];
#pragma unroll
            for (int r = 0; r < 4; ++r) sc_r[r] = __shfl(sc, lg * 4 + r);
#pragma unroll
            for (int hs = 0; hs < 8; ++hs)
#pragma unroll
                for (int r = 0; r < 4; ++r) oacc[hs][r] *= sc_r[r];
            m_r = newm;
        }

#pragma unroll
        for (int ms = 0; ms < 4; ++ms) {
            const float p0 = __expf(sv[ms][0] - m_r);
            const float p1 = __expf(sv[ms][1] - m_r);
            const float p2 = __expf(sv[ms][2] - m_r);
            const float p3 = __expf(sv[ms][3] - m_r);
            lsum += (p0 + p1) + (p2 + p3);
            const int lin = lq * 128 + ms * 32 + lg * 8;
            const int ad  = lin ^ ((lq & 7) << 4);
            *(unsigned int*)(ldsP + ad)     = cvtpk(p0, p1);
            *(unsigned int*)(ldsP + ad + 4) = cvtpk(p2, p3);
        }

        __builtin_amdgcn_s_setprio(1);
#pragma unroll
        for (int msl = 0; msl < 2; ++msl) {
            bf16x8 pf = *(const bf16x8*)(ldsP + ((lq * 128 + msl * 64 + lg * 16) ^ ((lq & 7) << 4)));
#pragma unroll
            for (int hs = 0; hs < 8; ++hs) {
                const int hrow = hs * 16 + lq;
                bf16x8 vf = *(const bf16x8*)(ldsV + ((hrow * 128 + msl * 64 + lg * 16) ^ ((hrow & 7) << 4)));
                oacc[hs] = __builtin_amdgcn_mfma_f32_16x16x32_bf16(pf, vf, oacc[hs], 0, 0, 0);
            }
        }
        __builtin_amdgcn_s_setprio(0);
    }

    lsum += __shfl_xor(lsum, 16);
    lsum += __shfl_xor(lsum, 32);
    // Acc layout [b][n][h]: lane holds n = q0+w*16+lg*4+r, h = hs*16+lq
    float* Ab = Ap + ((size_t)b * NPTS + q0 + w * 16) * HID;
#pragma unroll
    for (int hs = 0; hs < 8; ++hs) {
#pragma unroll
        for (int r = 0; r < 4; ++r)
            Ab[(size_t)(lg * 4 + r) * HID + hs * 16 + lq] = oacc[hs][r];
    }
    if (lg == 0) {
        Mp[b * NPTS + q0 + w * 16 + lq] = m_r;
        Lp[b * NPTS + q0 + w * 16 + lq] = lsum;
    }
}

// ---------------- combine 4 splits -> bf16 [nr][128] ----------------
__global__ __launch_bounds__(256) void fmha_combine_kernel(const float* __restrict__ A0,
                                                           const float* __restrict__ A1,
                                                           const float* __restrict__ A2,
                                                           const float* __restrict__ A3,
                                                           const float* __restrict__ Mb,
                                                           const float* __restrict__ Lb,
                                                           unsigned short* __restrict__ Ob) {
    const int i = blockIdx.x * 256 + threadIdx.x;
    const int nidx = i >> 7;
    const float m0 = Mb[nidx], m1 = Mb[NTOT + nidx];
    const float m2 = Mb[2 * NTOT + nidx], m3 = Mb[3 * NTOT + nidx];
    const float M = fmaxf(fmaxf(m0, m1), fmaxf(m2, m3));
    const float e0 = __expf(m0 - M), e1 = __expf(m1 - M);
    const float e2 = __expf(m2 - M), e3 = __expf(m3 - M);
    const float den = e0 * Lb[nidx] + e1 * Lb[NTOT + nidx]
                    + e2 * Lb[2 * NTOT + nidx] + e3 * Lb[3 * NTOT + nidx];
    const float num = e0 * A0[i] + e1 * A1[i] + e2 * A2[i] + e3 * A3[i];
    Ob[i] = f2bf(num / den);
}

// ---------------- softmax over N of pooling scores ----------------
__global__ __launch_bounds__(256) void softmax_w_kernel(float* __restrict__ s) {
    const int b = blockIdx.x;
    const int tid = threadIdx.x;
    __shared__ float red[256];
    float lm = -3.0e38f;
    for (int n = tid; n < NPTS; n += 256) lm = fmaxf(lm, s[b * NPTS + n]);
    red[tid] = lm;
    __syncthreads();
    for (int st = 128; st > 0; st >>= 1) {
        if (tid < st) red[tid] = fmaxf(red[tid], red[tid + st]);
        __syncthreads();
    }
    const float mx = red[0];
    __syncthreads();
    float ls = 0.f;
    for (int n = tid; n < NPTS; n += 256) {
        const float p = __expf(s[b * NPTS + n] - mx);
        s[b * NPTS + n] = p;
        ls += p;
    }
    red[tid] = ls;
    __syncthreads();
    for (int st = 128; st > 0; st >>= 1) {
        if (tid < st) red[tid] += red[tid + st];
        __syncthreads();
    }
    const float inv = 1.f / red[0];
    __syncthreads();
    for (int n = tid; n < NPTS; n += 256) s[b * NPTS + n] *= inv;
}

// ---------------- weighted pooling ----------------
__global__ __launch_bounds__(256) void pool3_kernel(const unsigned short* __restrict__ h,
                                                    const float* __restrict__ w,
                                                    float* __restrict__ pooled) {
    const int b  = blockIdx.y;
    const int n0 = blockIdx.x * 64;
    const int cg = (threadIdx.x & 63) * 4;
    const int rs = threadIdx.x >> 6;
    float a0 = 0.f, a1 = 0.f, a2 = 0.f, a3 = 0.f;
#pragma unroll 4
    for (int i = 0; i < 16; ++i) {
        const int n = n0 + i * 4 + rs;
        const ushort4 v = *(const ushort4*)(h + ((size_t)b * NPTS + n) * 256 + cg);
        const float wv = w[b * NPTS + n];
        a0 = fmaf(bf2f(v.x), wv, a0);
        a1 = fmaf(bf2f(v.y), wv, a1);
        a2 = fmaf(bf2f(v.z), wv, a2);
        a3 = fmaf(bf2f(v.w), wv, a3);
    }
    float* pp = pooled + b * 256 + cg;
    atomicAdd(pp + 0, a0);
    atomicAdd(pp + 1, a1);
    atomicAdd(pp + 2, a2);
    atomicAdd(pp + 3, a3);
}

// ---------------- final FC + ReLU ----------------
__global__ __launch_bounds__(256) void fc_kernel(const float* __restrict__ pooled,
                                                 const float* __restrict__ fcw,
                                                 const float* __restrict__ fcb,
                                                 float* __restrict__ out) {
    const int b = blockIdx.x, j = threadIdx.x;
    __shared__ float ps[256];
    ps[j] = pooled[b * 256 + j];
    __syncthreads();
    float acc = fcb[j];
    for (int c = 0; c < 256; ++c) acc = fmaf(ps[c], fcw[j * 256 + c], acc);
    out[b * 256 + j] = fmaxf(acc, 0.f);
}

extern "C" void kernel_launch(void* const* d_in, const int* in_sizes, int n_in,
                              void* d_out, int out_size, void* d_ws, size_t ws_size,
                              hipStream_t stream) {
    const float* x   = (const float*)d_in[0];
    const float* w1  = (const float*)d_in[1];
    const float* b1  = (const float*)d_in[2];
    const float* g1  = (const float*)d_in[3];
    const float* be1 = (const float*)d_in[4];
    const float* w2  = (const float*)d_in[5];
    const float* b2  = (const float*)d_in[6];
    const float* g2  = (const float*)d_in[7];
    const float* be2 = (const float*)d_in[8];
    const float* w3  = (const float*)d_in[9];
    const float* b3  = (const float*)d_in[10];
    const float* g3  = (const float*)d_in[11];
    const float* be3 = (const float*)d_in[12];
    const float* qw  = (const float*)d_in[13];
    const float* qb  = (const float*)d_in[14];
    const float* kw  = (const float*)d_in[15];
    const float* kb  = (const float*)d_in[16];
    const float* vw  = (const float*)d_in[17];
    const float* vb  = (const float*)d_in[18];
    const float* fw  = (const float*)d_in[19];
    const float* fb  = (const float*)d_in[20];
    const float* aw1 = (const float*)d_in[21];
    const float* ab1 = (const float*)d_in[22];
    const float* aw2 = (const float*)d_in[23];
    const float* ab2 = (const float*)d_in[24];
    const float* fcw = (const float*)d_in[25];
    const float* fcb = (const float*)d_in[26];

    // ---- workspace layout (f32 units), lifetime-checked arenas ----
    float* ws = (float*)d_ws;
    float* h0     = ws;
    float* arena1 = h0 + 294912;           // y1/y2/y3 -> Acc2|Acc3
    float* arena2 = arena1 + 4194304;      // h3b
    float* arena3 = arena2 + 2097152;      // h1b -> h2b -> Qb -> OBF
    float* arena4 = arena3 + 1048576;      // Kb
    float* arena5 = arena4 + 1048576;      // Vb
    float* arena6 = arena5 + 1048576;      // Acc0 -> h4b
    float* arena7 = arena6 + 2097152;      // Acc1
    float* Mls    = arena7 + 2097152;      // M[4][NTOT] | L[4][NTOT]
    float* s      = Mls + 131072;
    float* pooled = s + 16384;
    float* mstats = pooled + 1024;
    float* wbf    = mstats + 512;
    float* xyzwp  = wbf + 94208;
    float* parts  = xyzwp + 65536;

    float* y1 = arena1;
    float* y2 = arena1;
    float* y3 = arena1;
    unsigned short* H1b = (unsigned short*)arena3;
    unsigned short* H2b = (unsigned short*)arena3;
    unsigned short* Qb  = (unsigned short*)arena3;
    unsigned short* OBF = (unsigned short*)arena3;
    unsigned short* H3b = (unsigned short*)arena2;
    unsigned short* Kb  = (unsigned short*)arena4;
    unsigned short* Vb  = (unsigned short*)arena5;
    float* Acc0 = arena6;
    unsigned short* H4b = (unsigned short*)arena6;
    float* Acc1 = arena7;
    float* Acc2 = arena1;
    float* Acc3 = arena1 + 2097152;
    float* Mb = Mls;
    float* Lb = Mls + 4 * NTOT;
    unsigned short* WB = (unsigned short*)wbf;
    unsigned short* w2b  = WB;
    unsigned short* w3b  = WB + 8192;
    unsigned short* qwb  = WB + 40960;
    unsigned short* fwb  = WB + 139264;
    unsigned short* aw1b = WB + 172032;
    float4* xyzw = (float4*)xyzwp;

    hipMemsetAsync(pooled, 0, 1024 * sizeof(float), stream);
    prep_kernel<<<dim3(736), 256, 0, stream>>>(x, xyzw, w2, w3, qw, kw, vw, fw, aw1, WB);
    knn3_kernel<<<dim3(NTOT / 8), 256, 0, stream>>>(x, xyzw, h0);

    conv1_kernel<<<dim3(NPTS / 64, 4, B), 256, 0, stream>>>(h0, w1, b1, y1, parts);
    finstats_kernel<<<64, 64, 0, stream>>>(parts, mstats, 64);
    bnapply_kernel<<<dim3(NTOT * 64 / 1024), 256, 0, stream>>>(y1, mstats, g1, be1, H1b, 64);
    gemm_kernel<64, 0><<<dim3(NTOT / 64, 2), 256, 0, stream>>>(H1b, w2b, b2, nullptr, y2, 128, parts);
    finstats_kernel<<<128, 64, 0, stream>>>(parts, mstats, 128);
    bnapply_kernel<<<dim3(NTOT * 128 / 1024), 256, 0, stream>>>(y2, mstats, g2, be2, H2b, 128);
    gemm_kernel<128, 0><<<dim3(NTOT / 64, 4), 256, 0, stream>>>(H2b, w3b, b3, nullptr, y3, 256, parts);
    finstats_kernel<<<256, 64, 0, stream>>>(parts, mstats, 256);
    bnapply_kernel<<<dim3(NTOT * 256 / 1024), 256, 0, stream>>>(y3, mstats, g3, be3, H3b, 256);

    qkv_kernel<<<dim3(NTOT / 64, 6), 256, 0, stream>>>(H3b, qwb, qb, kb, vb, Qb, Kb, Vb);

    fmha2_kernel<<<dim3(NPTS / QR, B, NSPL), 256, 0, stream>>>(Qb, Kb, Vb, Acc0, Acc1, Acc2, Acc3, Mb, Lb);
    fmha_combine_kernel<<<dim3(NTOT * HID / 256), 256, 0, stream>>>(Acc0, Acc1, Acc2, Acc3, Mb, Lb, OBF);

    gemm_kernel<128, 3><<<dim3(NTOT / 64, 4), 256, 0, stream>>>(OBF, fwb, fb, H3b, H4b, 256, nullptr);
    gemm_kernel<256, 5><<<dim3(NTOT / 64, 1), 256, 0, stream>>>(H4b, aw1b, ab1,
                                                                (const unsigned short*)aw2, s, 64, (float*)ab2);

    softmax_w_kernel<<<B, 256, 0, stream>>>(s);
    pool3_kernel<<<dim3(64, B), 256, 0, stream>>>(H4b, s, pooled);
    fc_kernel<<<B, 256, 0, stream>>>(pooled, fcw, fcb, (float*)d_out);

    (void)in_sizes; (void)n_in; (void)out_size; (void)ws_size;
}

// Round 17
// 243.698 us; speedup vs baseline: 1.0562x; 1.0049x over previous
//
#include <hip/hip_runtime.h>
#include <math.h>

constexpr int B    = 4;
constexpr int NPTS = 4096;
constexpr int NTOT = B * NPTS;
constexpr int CIN  = 9;
constexpr int C0   = 18;
constexpr int KNB  = 8;
constexpr int HID  = 128;
constexpr int QR   = 64;    // q rows per fmha block
constexpr int KC   = 64;    // m per fmha tile
constexpr int NSPL = 4;     // fmha KV splits
constexpr float EPSF = 1e-5f;

using f32x4  = __attribute__((ext_vector_type(4))) float;
using bf16x8 = __attribute__((ext_vector_type(8))) short;

__device__ inline unsigned short f2bf(float f) {
    unsigned int x = __float_as_uint(f);
    unsigned int r = (x + 0x7fffu + ((x >> 16) & 1u)) >> 16;
    return (unsigned short)r;
}
__device__ inline float bf2f(unsigned short u) {
    return __uint_as_float(((unsigned int)u) << 16);
}
// HW packed f32->bf16 (RNE), validated round 13
__device__ inline unsigned int cvtpk(float lo, float hi) {
    unsigned int r;
    asm("v_cvt_pk_bf16_f32 %0, %1, %2" : "=v"(r) : "v"(lo), "v"(hi));
    return r;
}

#define GLD_LDS16(g, l) __builtin_amdgcn_global_load_lds( \
    (const __attribute__((address_space(1))) void*)(g),   \
    (__attribute__((address_space(3))) void*)(l), 16, 0, 0)

// ---------------- prep: weight pack f32->bf16 (7 segments) + xyz pack ----------------
__global__ __launch_bounds__(256) void prep_kernel(const float* __restrict__ x,
                                                   float4* __restrict__ xyzw,
                                                   const float* __restrict__ w2,
                                                   const float* __restrict__ w3,
                                                   const float* __restrict__ qw,
                                                   const float* __restrict__ kw,
                                                   const float* __restrict__ vw,
                                                   const float* __restrict__ fw,
                                                   const float* __restrict__ aw1,
                                                   unsigned short* __restrict__ dst) {
    const int i = blockIdx.x * 256 + threadIdx.x;   // 188416 total
    if (i < NTOT) {
        const float* xp = x + (size_t)i * CIN;
        const float a = xp[0], b = xp[1], c = xp[2];
        xyzw[i] = make_float4(a, b, c, a * a + b * b + c * c);
    }
    const float* src;
    int off;
    if      (i <   8192) { src = w2;  off = 0; }
    else if (i <  40960) { src = w3;  off = 8192; }
    else if (i <  73728) { src = qw;  off = 40960; }
    else if (i < 106496) { src = kw;  off = 73728; }
    else if (i < 139264) { src = vw;  off = 106496; }
    else if (i < 172032) { src = fw;  off = 139264; }
    else                 { src = aw1; off = 172032; }
    dst[i] = f2bf(src[i - off]);
}

// ---------------- KNN v5: packed u32 (dist20|idx12) keys ----------------
__global__ __launch_bounds__(256) void knn3_kernel(const float* __restrict__ x,
                                                   const float4* __restrict__ xyzw,
                                                   float* __restrict__ h0) {
    __shared__ __align__(16) char lds[16384];
    const int tid = threadIdx.x;
    const int w = tid >> 6, l = tid & 63;
    const int b  = blockIdx.x >> 9;
    const int p0 = (blockIdx.x & 511) << 3;
    const int c  = l & 31;
    const int n  = p0 + w * 2 + (l >> 5);
    const float4* xb4 = xyzw + (size_t)b * NPTS;

    const float4 q4 = xb4[n];
    const float qx = q4.x, qy = q4.y, qz = q4.z, sqn = q4.w;

    unsigned int bd[KNB];
#pragma unroll
    for (int i = 0; i < KNB; ++i) bd[i] = 0xFFFFFFFFu;

    auto stage = [&](int buf, int t) {
#pragma unroll
        for (int i = 0; i < 2; ++i) {
            const int idx = i * 256 + w * 64 + l;
            const int m   = idx ^ ((idx >> 4) & 7);
            GLD_LDS16(xb4 + (size_t)t * 512 + m, lds + buf * 8192 + i * 4096 + w * 1024);
        }
    };

    stage(0, 0);
#pragma unroll 2
    for (int t = 0; t < 8; ++t) {
        const int cur = t & 1;
        __syncthreads();
        if (t < 7) stage(cur ^ 1, t + 1);

        const char* buf = lds + cur * 8192 + c * 256;
        const int mbase = t * 512 + c * 16;
        const int cswz  = (c & 7) << 4;
#pragma unroll 4
        for (int j = 0; j < 16; ++j) {
            const float4 f4 = *(const float4*)(buf + ((j << 4) ^ cswz));
            const float tt = fmaf(qx, f4.x, fmaf(qy, f4.y, qz * f4.z));
            const float d2 = fmaxf(fmaf(-2.0f, tt, sqn + f4.w), 0.f);
            const int m = mbase + j;
            unsigned int key = (__float_as_uint(d2) & 0xFFFFF000u) | (unsigned int)m;
            if (m == n) key = 0xFFFFFFFFu;
            bd[KNB - 1] = min(bd[KNB - 1], key);
#pragma unroll
            for (int s = KNB - 1; s > 0; --s) {
                const unsigned int lo = min(bd[s - 1], bd[s]);
                const unsigned int hi = max(bd[s - 1], bd[s]);
                bd[s - 1] = lo; bd[s] = hi;
            }
        }
    }

    unsigned int res[KNB];
#pragma unroll
    for (int r = 0; r < KNB; ++r) {
        unsigned int v = bd[0];
#pragma unroll
        for (int mask = 16; mask > 0; mask >>= 1)
            v = min(v, (unsigned int)__shfl_xor((int)v, mask));
        res[r] = v;
        if (bd[0] == v) {
#pragma unroll
            for (int s = 0; s < KNB - 1; ++s) bd[s] = bd[s + 1];
            bd[KNB - 1] = 0xFFFFFFFFu;
        }
    }

    const int c8 = c & 7;
    unsigned int kk = res[0];
#pragma unroll
    for (int k = 1; k < KNB; ++k) kk = (c8 == k) ? res[k] : kk;
    const int nb = (int)(kk & 0xFFFu);
    const float* xb = x + (size_t)b * NPTS * CIN;
    float nv[CIN];
    const float* nbp = xb + (size_t)nb * CIN;
#pragma unroll
    for (int ch = 0; ch < CIN; ++ch) nv[ch] = nbp[ch];
#pragma unroll
    for (int d = 1; d < 8; d <<= 1) {
#pragma unroll
        for (int ch = 0; ch < CIN; ++ch) nv[ch] += __shfl_xor(nv[ch], d);
    }
    const int ch = min(c, 8);
    float nvc = nv[0];
#pragma unroll
    for (int k = 1; k < CIN; ++k) nvc = (ch == k) ? nv[k] : nvc;
    if (c < 9) {
        const float xv = xb[(size_t)n * CIN + ch];
        h0[((size_t)b * C0 + ch) * NPTS + n]       = nvc * 0.125f - xv;
        h0[((size_t)b * C0 + CIN + ch) * NPTS + n] = xv;
    }
}

// ---------------- layer-1 conv (fp32, C=18) + partial stats ----------------
__global__ __launch_bounds__(256) void conv1_kernel(const float* __restrict__ X,
                                                    const float* __restrict__ W,
                                                    const float* __restrict__ bias,
                                                    float* __restrict__ Y,
                                                    float* __restrict__ parts) {
    __shared__ float Ws[16 * C0];
    const int b  = blockIdx.z;
    const int o_base = blockIdx.y * 16;
    const int l  = threadIdx.x & 63;
    const int n  = blockIdx.x * 64 + l;
    const int og = threadIdx.x >> 6;
    for (int i = threadIdx.x; i < 16 * C0; i += 256)
        Ws[i] = W[(size_t)o_base * C0 + i];
    __syncthreads();
    float acc[4] = {0.f, 0.f, 0.f, 0.f};
    const float* Xp = X + (size_t)b * C0 * NPTS + n;
    for (int c = 0; c < C0; ++c) {
        const float xv = Xp[(size_t)c * NPTS];
#pragma unroll
        for (int i = 0; i < 4; ++i)
            acc[i] = fmaf(Ws[(og * 4 + i) * C0 + c], xv, acc[i]);
    }
    f32x4 v;
#pragma unroll
    for (int i = 0; i < 4; ++i) v[i] = acc[i] + bias[o_base + og * 4 + i];
    *(f32x4*)(Y + ((size_t)b * NPTS + n) * 64 + o_base + og * 4) = v;
    float s1[4], s2[4];
#pragma unroll
    for (int i = 0; i < 4; ++i) { s1[i] = v[i]; s2[i] = v[i] * v[i]; }
#pragma unroll
    for (int d = 1; d < 64; d <<= 1) {
#pragma unroll
        for (int i = 0; i < 4; ++i) {
            s1[i] += __shfl_xor(s1[i], d);
            s2[i] += __shfl_xor(s2[i], d);
        }
    }
    if (l == 0) {
        const int rg = blockIdx.z * 64 + blockIdx.x;
#pragma unroll
        for (int i = 0; i < 4; ++i) {
            const int ch = o_base + og * 4 + i;
            parts[ch * 256 + rg]            = s1[i];
            parts[64 * 256 + ch * 256 + rg] = s2[i];
        }
    }
}

// ---------------- finalize stats ----------------
__global__ __launch_bounds__(64) void finstats_kernel(const float* __restrict__ parts,
                                                      float* __restrict__ mstats, int O) {
    const int ch = blockIdx.x, l = threadIdx.x;
    const f32x4 a1 = *(const f32x4*)(parts + (size_t)ch * 256 + l * 4);
    const f32x4 a2 = *(const f32x4*)(parts + (size_t)O * 256 + (size_t)ch * 256 + l * 4);
    float s1 = (a1[0] + a1[1]) + (a1[2] + a1[3]);
    float s2 = (a2[0] + a2[1]) + (a2[2] + a2[3]);
#pragma unroll
    for (int d = 1; d < 64; d <<= 1) {
        s1 += __shfl_xor(s1, d);
        s2 += __shfl_xor(s2, d);
    }
    if (l == 0) {
        const float mean = s1 * (1.0f / NTOT);
        const float var  = s2 * (1.0f / NTOT) - mean * mean;
        mstats[ch]     = mean;
        mstats[O + ch] = rsqrtf(var + EPSF);
    }
}

// ---------------- BN apply + ReLU -> bf16 ----------------
__global__ __launch_bounds__(256) void bnapply_kernel(const float* __restrict__ Y,
                                                      const float* __restrict__ mstats,
                                                      const float* __restrict__ g,
                                                      const float* __restrict__ be,
                                                      unsigned short* __restrict__ Yb,
                                                      int O) {
    const size_t i4 = (size_t)blockIdx.x * 256 + threadIdx.x;
    const int cbase = (int)((i4 * 4) & (O - 1));
    const f32x4 v = *(const f32x4*)(Y + i4 * 4);
    ushort4 pk;
    unsigned short* pp = (unsigned short*)&pk;
#pragma unroll
    for (int r = 0; r < 4; ++r) {
        const int c = cbase + r;
        const float y = fmaxf(g[c] * mstats[O + c] * (v[r] - mstats[c]) + be[c], 0.f);
        pp[r] = f2bf(y);
    }
    *(ushort4*)(Yb + i4 * 4) = pk;
}

// ---------------- bf16 MFMA GEMM ----------------
// EPI: 0 = f32 out + partial-stats stores; 1 = bf16 bias; 2 = bf16 bias+relu;
//      3 = bf16 bias+residual; 4 = V-transpose bf16 bias;
//      5 = relu + fused aw2 dot -> s[nr] (resid carries aw2, parts carries ab2)
template <int C, int EPI>
__global__ __launch_bounds__(256) void gemm_kernel(const unsigned short* __restrict__ A,
                                                   const unsigned short* __restrict__ Wb,
                                                   const float* __restrict__ bias,
                                                   const unsigned short* __restrict__ resid,
                                                   void* __restrict__ Yv, int O,
                                                   float* __restrict__ parts) {
    constexpr int RB = 2 * C;
    constexpr int SLOTS = C / 8;
    __shared__ __align__(16) char ldsW[64 * RB];
    const int tid = threadIdx.x;
    const int w = tid >> 6, l = tid & 63;
    const int lg = l >> 4, lq = l & 15;
    const int n0 = blockIdx.x * 64;
    const int o0 = blockIdx.y * 64;

#pragma unroll
    for (int i = 0; i < C / 32; ++i) {
        const int idx = i * 256 + tid;
        const int m  = idx / SLOTS;
        const int sl = (idx % SLOTS) ^ (m & 7);
        GLD_LDS16(Wb + (size_t)(o0 + m) * C + sl * 8, ldsW + (i * 256 + w * 64) * 16);
    }

    const int nr = n0 + w * 16 + lq;
    const unsigned short* Ap = A + (size_t)nr * C + lg * 8;
    f32x4 acc[4];
#pragma unroll
    for (int os = 0; os < 4; ++os) acc[os] = {0.f, 0.f, 0.f, 0.f};
    __syncthreads();

#pragma unroll
    for (int ks = 0; ks < C / 32; ++ks) {
        const bf16x8 af = *(const bf16x8*)(Ap + ks * 32);
#pragma unroll
        for (int os = 0; os < 4; ++os) {
            const int row = os * 16 + lq;
            const bf16x8 wf = *(const bf16x8*)(ldsW + ((row * RB + ks * 64 + lg * 16) ^ ((lq & 7) << 4)));
            acc[os] = __builtin_amdgcn_mfma_f32_16x16x32_bf16(wf, af, acc[os], 0, 0, 0);
        }
    }

    f32x4 vv[4];
    float dotacc = 0.f;
#pragma unroll
    for (int os = 0; os < 4; ++os) {
        const int ob = o0 + os * 16 + lg * 4;
        const f32x4 bv = *(const f32x4*)(bias + ob);
#pragma unroll
        for (int r = 0; r < 4; ++r) vv[os][r] = acc[os][r] + bv[r];
        if (EPI == 0) {
            *(f32x4*)((float*)Yv + (size_t)nr * O + ob) = vv[os];
        } else if (EPI == 4) {
            unsigned short* Y = (unsigned short*)Yv;
            const int bb = nr >> 12, n = nr & (NPTS - 1);
#pragma unroll
            for (int r = 0; r < 4; ++r)
                Y[((size_t)bb * HID + ob + r) * NPTS + n] = f2bf(vv[os][r]);
        } else if (EPI == 5) {
            const f32x4 w2v = *(const f32x4*)((const float*)resid + ob);
#pragma unroll
            for (int r = 0; r < 4; ++r)
                dotacc = fmaf(fmaxf(vv[os][r], 0.f), w2v[r], dotacc);
        } else {
            f32x4 v = vv[os];
            if (EPI == 3) {
                const ushort4 rv = *(const ushort4*)(resid + (size_t)nr * O + ob);
                v[0] += bf2f(rv.x); v[1] += bf2f(rv.y); v[2] += bf2f(rv.z); v[3] += bf2f(rv.w);
            }
            if (EPI == 2) {
#pragma unroll
                for (int r = 0; r < 4; ++r) v[r] = fmaxf(v[r], 0.f);
            }
            ushort4 pk;
            pk.x = f2bf(v[0]); pk.y = f2bf(v[1]); pk.z = f2bf(v[2]); pk.w = f2bf(v[3]);
            *(ushort4*)((unsigned short*)Yv + (size_t)nr * O + ob) = pk;
        }
    }

    if (EPI == 5) {
        dotacc += __shfl_xor(dotacc, 16);
        dotacc += __shfl_xor(dotacc, 32);
        if (lg == 0) ((float*)Yv)[nr] = dotacc + ((const float*)parts)[0];
    }

    if (EPI == 0) {
        float* sred = (float*)ldsW;
        float s1[4][4], s2[4][4];
#pragma unroll
        for (int os = 0; os < 4; ++os)
#pragma unroll
            for (int r = 0; r < 4; ++r) {
                float a1 = vv[os][r], a2 = vv[os][r] * vv[os][r];
#pragma unroll
                for (int d = 1; d < 16; d <<= 1) {
                    a1 += __shfl_xor(a1, d);
                    a2 += __shfl_xor(a2, d);
                }
                s1[os][r] = a1; s2[os][r] = a2;
            }
        __syncthreads();
        if (lq == 0) {
#pragma unroll
            for (int os = 0; os < 4; ++os)
#pragma unroll
                for (int r = 0; r < 4; ++r) {
                    const int ch = os * 16 + lg * 4 + r;
                    sred[(w * 64 + ch) * 2 + 0] = s1[os][r];
                    sred[(w * 64 + ch) * 2 + 1] = s2[os][r];
                }
        }
        __syncthreads();
        if (tid < 128) {
            const int ch = tid & 63, st = tid >> 6;
            const float a = sred[ch * 2 + st] + sred[(64 + ch) * 2 + st]
                          + sred[(128 + ch) * 2 + st] + sred[(192 + ch) * 2 + st];
            parts[(size_t)st * O * 256 + (size_t)(o0 + ch) * 256 + blockIdx.x] = a;
        }
    }
}

// ---------------- fused QKV projection ----------------
__global__ __launch_bounds__(256) void qkv_kernel(const unsigned short* __restrict__ A,
                                                  const unsigned short* __restrict__ Wall,
                                                  const float* __restrict__ qb,
                                                  const float* __restrict__ kb,
                                                  const float* __restrict__ vb,
                                                  unsigned short* __restrict__ Qo,
                                                  unsigned short* __restrict__ Ko,
                                                  unsigned short* __restrict__ Vo) {
    constexpr int C = 256, RB = 512, SLOTS = 32;
    __shared__ __align__(16) char ldsW[64 * RB];
    const int tid = threadIdx.x;
    const int w = tid >> 6, l = tid & 63;
    const int lg = l >> 4, lq = l & 15;
    const int n0 = blockIdx.x * 64;
    const int by = blockIdx.y;
    const int proj = by >> 1;
    const int o0 = (by & 1) * 64;
    const unsigned short* Wb = Wall + (size_t)proj * 32768;
    const float* bias = (proj == 0) ? qb : (proj == 1) ? kb : vb;

#pragma unroll
    for (int i = 0; i < C / 32; ++i) {
        const int idx = i * 256 + tid;
        const int m  = idx / SLOTS;
        const int sl = (idx % SLOTS) ^ (m & 7);
        GLD_LDS16(Wb + (size_t)(o0 + m) * C + sl * 8, ldsW + (i * 256 + w * 64) * 16);
    }

    const int nr = n0 + w * 16 + lq;
    const unsigned short* Ap = A + (size_t)nr * C + lg * 8;
    f32x4 acc[4];
#pragma unroll
    for (int os = 0; os < 4; ++os) acc[os] = {0.f, 0.f, 0.f, 0.f};
    __syncthreads();

#pragma unroll
    for (int ks = 0; ks < C / 32; ++ks) {
        const bf16x8 af = *(const bf16x8*)(Ap + ks * 32);
#pragma unroll
        for (int os = 0; os < 4; ++os) {
            const int row = os * 16 + lq;
            const bf16x8 wf = *(const bf16x8*)(ldsW + ((row * RB + ks * 64 + lg * 16) ^ ((lq & 7) << 4)));
            acc[os] = __builtin_amdgcn_mfma_f32_16x16x32_bf16(wf, af, acc[os], 0, 0, 0);
        }
    }

#pragma unroll
    for (int os = 0; os < 4; ++os) {
        const int ob = o0 + os * 16 + lg * 4;
        const f32x4 bv = *(const f32x4*)(bias + ob);
        f32x4 v;
#pragma unroll
        for (int r = 0; r < 4; ++r) v[r] = acc[os][r] + bv[r];
        if (proj < 2) {
            unsigned short* Y = proj ? Ko : Qo;
            ushort4 pk;
            pk.x = f2bf(v[0]); pk.y = f2bf(v[1]); pk.z = f2bf(v[2]); pk.w = f2bf(v[3]);
            *(ushort4*)(Y + (size_t)nr * 128 + ob) = pk;
        } else {
            const int bb = nr >> 12, n = nr & (NPTS - 1);
#pragma unroll
            for (int r = 0; r < 4; ++r)
                Vo[((size_t)bb * HID + ob + r) * NPTS + n] = f2bf(v[r]);
        }
    }
}

// ---------------- fmha staging: 64x128 K tile + 128x64 V tile (16KB each) ----------------
__device__ __forceinline__ void stage_tile(char* lds, int buf,
                                           const unsigned short* Kb,
                                           const unsigned short* Vb,
                                           int n0, int w, int l) {
    char* dK = lds + buf * 16384;
    char* dV = lds + 32768 + buf * 16384;
#pragma unroll
    for (int j = 0; j < 4; ++j) {
        const int y = w * 4096 + j * 1024 + l * 16;
        const int m = y >> 8;
        const int slot = ((y >> 4) & 15) ^ (m & 7);
        GLD_LDS16(Kb + (size_t)(n0 + m) * HID + slot * 8, dK + w * 4096 + j * 1024);
    }
#pragma unroll
    for (int j = 0; j < 4; ++j) {
        const int y = w * 4096 + j * 1024 + l * 16;
        const int h = y >> 7;
        const int slot = ((y >> 4) & 7) ^ (h & 7);
        GLD_LDS16(Vb + (size_t)h * NPTS + n0 + slot * 8, dV + w * 4096 + j * 1024);
    }
}

// ---------------- MFMA flash attention (round-12 proven structure), KV-split x4 ----------------
__global__ __launch_bounds__(256) void fmha2_kernel(const unsigned short* __restrict__ Qg,
                                                    const unsigned short* __restrict__ Kg,
                                                    const unsigned short* __restrict__ Vg,
                                                    float* __restrict__ A0, float* __restrict__ A1,
                                                    float* __restrict__ A2, float* __restrict__ A3,
                                                    float* __restrict__ Mb, float* __restrict__ Lb) {
    __shared__ __align__(16) char lds[73728];   // K dbuf 32K | V dbuf 32K | P 4x2K
    const int tid = threadIdx.x;
    const int w = tid >> 6, l = tid & 63;
    const int lg = l >> 4, lq = l & 15;
    const int b  = blockIdx.y;
    const int q0 = blockIdx.x * QR;
    const int split = blockIdx.z;
    const int n0base = split * (NPTS / NSPL);
    float* Ap = (split == 0) ? A0 : (split == 1) ? A1 : (split == 2) ? A2 : A3;
    float* Mp = Mb + split * NTOT;
    float* Lp = Lb + split * NTOT;
    char* ldsP = lds + 65536 + w * 2048;

    bf16x8 qf[4];
    {
        const unsigned short* qp = Qg + ((size_t)b * NPTS + q0 + w * 16 + lq) * HID + lg * 8;
#pragma unroll
        for (int ks = 0; ks < 4; ++ks)
            qf[ks] = *(const bf16x8*)(qp + ks * 32);
    }
    const unsigned short* Kb = Kg + (size_t)b * NPTS * HID;
    const unsigned short* Vb = Vg + (size_t)b * HID * NPTS;

    float m_r = -3.0e38f;
    float lsum = 0.f;
    f32x4 oacc[8];
#pragma unroll
    for (int hs = 0; hs < 8; ++hs) oacc[hs] = {0.f, 0.f, 0.f, 0.f};

    constexpr int NT = (NPTS / NSPL) / KC;
    stage_tile(lds, 0, Kb, Vb, n0base, w, l);

#pragma unroll 2
    for (int t = 0; t < NT; ++t) {
        const int cur = t & 1;
        __syncthreads();
        if (t + 1 < NT)
            stage_tile(lds, cur ^ 1, Kb, Vb, n0base + (t + 1) * KC, w, l);
        char* ldsK = lds + cur * 16384;
        char* ldsV = lds + 32768 + cur * 16384;

        f32x4 sv[4];
        __builtin_amdgcn_s_setprio(1);
#pragma unroll
        for (int ms = 0; ms < 4; ++ms) {
            const int row = ms * 16 + lq;
            f32x4 s = {0.f, 0.f, 0.f, 0.f};
#pragma unroll
            for (int ks = 0; ks < 4; ++ks) {
                bf16x8 kf = *(const bf16x8*)(ldsK + ((row * 256 + ks * 64 + lg * 16) ^ ((row & 7) << 4)));
                s = __builtin_amdgcn_mfma_f32_16x16x32_bf16(kf, qf[ks], s, 0, 0, 0);
            }
            sv[ms] = s;
        }
        __builtin_amdgcn_s_setprio(0);

        float pmax = sv[0][0];
#pragma unroll
        for (int ms = 0; ms < 4; ++ms)
#pragma unroll
            for (int r = 0; r < 4; ++r) pmax = fmaxf(pmax, sv[ms][r]);
        pmax = fmaxf(pmax, __shfl_xor(pmax, 16));
        pmax = fmaxf(pmax, __shfl_xor(pmax, 32));

        if (__any(pmax > m_r + 8.0f)) {
            const float newm = fmaxf(m_r, pmax);
            const float sc = __expf(m_r - newm);
            lsum *= sc;
            float sc_r[4];
#pragma unroll
            for (int r = 0; r < 4; ++r) sc_r[r] = __shfl(sc, lg * 4 + r);
#pragma unroll
            for (int hs = 0; hs < 8; ++hs)
#pragma unroll
                for (int r = 0; r < 4; ++r) oacc[hs][r] *= sc_r[r];
            m_r = newm;
        }

#pragma unroll
        for (int ms = 0; ms < 4; ++ms) {
            const float p0 = __expf(sv[ms][0] - m_r);
            const float p1 = __expf(sv[ms][1] - m_r);
            const float p2 = __expf(sv[ms][2] - m_r);
            const float p3 = __expf(sv[ms][3] - m_r);
            lsum += (p0 + p1) + (p2 + p3);
            const int lin = lq * 128 + ms * 32 + lg * 8;
            const int ad  = lin ^ ((lq & 7) << 4);
            *(unsigned int*)(ldsP + ad)     = cvtpk(p0, p1);
            *(unsigned int*)(ldsP + ad + 4) = cvtpk(p2, p3);
        }

        __builtin_amdgcn_s_setprio(1);
#pragma unroll
        for (int msl = 0; msl < 2; ++msl) {
            bf16x8 pf = *(const bf16x8*)(ldsP + ((lq * 128 + msl * 64 + lg * 16) ^ ((lq & 7) << 4)));
#pragma unroll
            for (int hs = 0; hs < 8; ++hs) {
                const int hrow = hs * 16 + lq;
                bf16x8 vf = *(const bf16x8*)(ldsV + ((hrow * 128 + msl * 64 + lg * 16) ^ ((hrow & 7) << 4)));
                oacc[hs] = __builtin_amdgcn_mfma_f32_16x16x32_bf16(pf, vf, oacc[hs], 0, 0, 0);
            }
        }
        __builtin_amdgcn_s_setprio(0);
    }

    lsum += __shfl_xor(lsum, 16);
    lsum += __shfl_xor(lsum, 32);
    // Acc layout [b][n][h]: lane holds n = q0+w*16+lg*4+r, h = hs*16+lq
    float* Ab = Ap + ((size_t)b * NPTS + q0 + w * 16) * HID;
#pragma unroll
    for (int hs = 0; hs < 8; ++hs) {
#pragma unroll
        for (int r = 0; r < 4; ++r)
            Ab[(size_t)(lg * 4 + r) * HID + hs * 16 + lq] = oacc[hs][r];
    }
    if (lg == 0) {
        Mp[b * NPTS + q0 + w * 16 + lq] = m_r;
        Lp[b * NPTS + q0 + w * 16 + lq] = lsum;
    }
}

// ---------------- combine 4 splits -> bf16 [nr][128] ----------------
__global__ __launch_bounds__(256) void fmha_combine_kernel(const float* __restrict__ A0,
                                                           const float* __restrict__ A1,
                                                           const float* __restrict__ A2,
                                                           const float* __restrict__ A3,
                                                           const float* __restrict__ Mb,
                                                           const float* __restrict__ Lb,
                                                           unsigned short* __restrict__ Ob) {
    const int i = blockIdx.x * 256 + threadIdx.x;
    const int nidx = i >> 7;
    const float m0 = Mb[nidx], m1 = Mb[NTOT + nidx];
    const float m2 = Mb[2 * NTOT + nidx], m3 = Mb[3 * NTOT + nidx];
    const float M = fmaxf(fmaxf(m0, m1), fmaxf(m2, m3));
    const float e0 = __expf(m0 - M), e1 = __expf(m1 - M);
    const float e2 = __expf(m2 - M), e3 = __expf(m3 - M);
    const float den = e0 * Lb[nidx] + e1 * Lb[NTOT + nidx]
                    + e2 * Lb[2 * NTOT + nidx] + e3 * Lb[3 * NTOT + nidx];
    const float num = e0 * A0[i] + e1 * A1[i] + e2 * A2[i] + e3 * A3[i];
    Ob[i] = f2bf(num / den);
}

// ---------------- softmax over N of pooling scores ----------------
__global__ __launch_bounds__(256) void softmax_w_kernel(float* __restrict__ s) {
    const int b = blockIdx.x;
    const int tid = threadIdx.x;
    __shared__ float red[256];
    float lm = -3.0e38f;
    for (int n = tid; n < NPTS; n += 256) lm = fmaxf(lm, s[b * NPTS + n]);
    red[tid] = lm;
    __syncthreads();
    for (int st = 128; st > 0; st >>= 1) {
        if (tid < st) red[tid] = fmaxf(red[tid], red[tid + st]);
        __syncthreads();
    }
    const float mx = red[0];
    __syncthreads();
    float ls = 0.f;
    for (int n = tid; n < NPTS; n += 256) {
        const float p = __expf(s[b * NPTS + n] - mx);
        s[b * NPTS + n] = p;
        ls += p;
    }
    red[tid] = ls;
    __syncthreads();
    for (int st = 128; st > 0; st >>= 1) {
        if (tid < st) red[tid] += red[tid + st];
        __syncthreads();
    }
    const float inv = 1.f / red[0];
    __syncthreads();
    for (int n = tid; n < NPTS; n += 256) s[b * NPTS + n] *= inv;
}

// ---------------- weighted pooling ----------------
__global__ __launch_bounds__(256) void pool3_kernel(const unsigned short* __restrict__ h,
                                                    const float* __restrict__ w,
                                                    float* __restrict__ pooled) {
    const int b  = blockIdx.y;
    const int n0 = blockIdx.x * 64;
    const int cg = (threadIdx.x & 63) * 4;
    const int rs = threadIdx.x >> 6;
    float a0 = 0.f, a1 = 0.f, a2 = 0.f, a3 = 0.f;
#pragma unroll 4
    for (int i = 0; i < 16; ++i) {
        const int n = n0 + i * 4 + rs;
        const ushort4 v = *(const ushort4*)(h + ((size_t)b * NPTS + n) * 256 + cg);
        const float wv = w[b * NPTS + n];
        a0 = fmaf(bf2f(v.x), wv, a0);
        a1 = fmaf(bf2f(v.y), wv, a1);
        a2 = fmaf(bf2f(v.z), wv, a2);
        a3 = fmaf(bf2f(v.w), wv, a3);
    }
    float* pp = pooled + b * 256 + cg;
    atomicAdd(pp + 0, a0);
    atomicAdd(pp + 1, a1);
    atomicAdd(pp + 2, a2);
    atomicAdd(pp + 3, a3);
}

// ---------------- final FC + ReLU ----------------
__global__ __launch_bounds__(256) void fc_kernel(const float* __restrict__ pooled,
                                                 const float* __restrict__ fcw,
                                                 const float* __restrict__ fcb,
                                                 float* __restrict__ out) {
    const int b = blockIdx.x, j = threadIdx.x;
    __shared__ float ps[256];
    ps[j] = pooled[b * 256 + j];
    __syncthreads();
    float acc = fcb[j];
    for (int c = 0; c < 256; ++c) acc = fmaf(ps[c], fcw[j * 256 + c], acc);
    out[b * 256 + j] = fmaxf(acc, 0.f);
}

extern "C" void kernel_launch(void* const* d_in, const int* in_sizes, int n_in,
                              void* d_out, int out_size, void* d_ws, size_t ws_size,
                              hipStream_t stream) {
    const float* x   = (const float*)d_in[0];
    const float* w1  = (const float*)d_in[1];
    const float* b1  = (const float*)d_in[2];
    const float* g1  = (const float*)d_in[3];
    const float* be1 = (const float*)d_in[4];
    const float* w2  = (const float*)d_in[5];
    const float* b2  = (const float*)d_in[6];
    const float* g2  = (const float*)d_in[7];
    const float* be2 = (const float*)d_in[8];
    const float* w3  = (const float*)d_in[9];
    const float* b3  = (const float*)d_in[10];
    const float* g3  = (const float*)d_in[11];
    const float* be3 = (const float*)d_in[12];
    const float* qw  = (const float*)d_in[13];
    const float* qb  = (const float*)d_in[14];
    const float* kw  = (const float*)d_in[15];
    const float* kb  = (const float*)d_in[16];
    const float* vw  = (const float*)d_in[17];
    const float* vb  = (const float*)d_in[18];
    const float* fw  = (const float*)d_in[19];
    const float* fb  = (const float*)d_in[20];
    const float* aw1 = (const float*)d_in[21];
    const float* ab1 = (const float*)d_in[22];
    const float* aw2 = (const float*)d_in[23];
    const float* ab2 = (const float*)d_in[24];
    const float* fcw = (const float*)d_in[25];
    const float* fcb = (const float*)d_in[26];

    // ---- workspace layout (f32 units), lifetime-checked arenas ----
    float* ws = (float*)d_ws;
    float* h0     = ws;
    float* arena1 = h0 + 294912;           // y1/y2/y3 -> Acc2|Acc3
    float* arena2 = arena1 + 4194304;      // h3b
    float* arena3 = arena2 + 2097152;      // h1b -> h2b -> Qb -> OBF
    float* arena4 = arena3 + 1048576;      // Kb
    float* arena5 = arena4 + 1048576;      // Vb
    float* arena6 = arena5 + 1048576;      // Acc0 -> h4b
    float* arena7 = arena6 + 2097152;      // Acc1
    float* Mls    = arena7 + 2097152;      // M[4][NTOT] | L[4][NTOT]
    float* s      = Mls + 131072;
    float* pooled = s + 16384;
    float* mstats = pooled + 1024;
    float* wbf    = mstats + 512;
    float* xyzwp  = wbf + 94208;
    float* parts  = xyzwp + 65536;

    float* y1 = arena1;
    float* y2 = arena1;
    float* y3 = arena1;
    unsigned short* H1b = (unsigned short*)arena3;
    unsigned short* H2b = (unsigned short*)arena3;
    unsigned short* Qb  = (unsigned short*)arena3;
    unsigned short* OBF = (unsigned short*)arena3;
    unsigned short* H3b = (unsigned short*)arena2;
    unsigned short* Kb  = (unsigned short*)arena4;
    unsigned short* Vb  = (unsigned short*)arena5;
    float* Acc0 = arena6;
    unsigned short* H4b = (unsigned short*)arena6;
    float* Acc1 = arena7;
    float* Acc2 = arena1;
    float* Acc3 = arena1 + 2097152;
    float* Mb = Mls;
    float* Lb = Mls + 4 * NTOT;
    unsigned short* WB = (unsigned short*)wbf;
    unsigned short* w2b  = WB;
    unsigned short* w3b  = WB + 8192;
    unsigned short* qwb  = WB + 40960;
    unsigned short* fwb  = WB + 139264;
    unsigned short* aw1b = WB + 172032;
    float4* xyzw = (float4*)xyzwp;

    hipMemsetAsync(pooled, 0, 1024 * sizeof(float), stream);
    prep_kernel<<<dim3(736), 256, 0, stream>>>(x, xyzw, w2, w3, qw, kw, vw, fw, aw1, WB);
    knn3_kernel<<<dim3(NTOT / 8), 256, 0, stream>>>(x, xyzw, h0);

    conv1_kernel<<<dim3(NPTS / 64, 4, B), 256, 0, stream>>>(h0, w1, b1, y1, parts);
    finstats_kernel<<<64, 64, 0, stream>>>(parts, mstats, 64);
    bnapply_kernel<<<dim3(NTOT * 64 / 1024), 256, 0, stream>>>(y1, mstats, g1, be1, H1b, 64);
    gemm_kernel<64, 0><<<dim3(NTOT / 64, 2), 256, 0, stream>>>(H1b, w2b, b2, nullptr, y2, 128, parts);
    finstats_kernel<<<128, 64, 0, stream>>>(parts, mstats, 128);
    bnapply_kernel<<<dim3(NTOT * 128 / 1024), 256, 0, stream>>>(y2, mstats, g2, be2, H2b, 128);
    gemm_kernel<128, 0><<<dim3(NTOT / 64, 4), 256, 0, stream>>>(H2b, w3b, b3, nullptr, y3, 256, parts);
    finstats_kernel<<<256, 64, 0, stream>>>(parts, mstats, 256);
    bnapply_kernel<<<dim3(NTOT * 256 / 1024), 256, 0, stream>>>(y3, mstats, g3, be3, H3b, 256);

    qkv_kernel<<<dim3(NTOT / 64, 6), 256, 0, stream>>>(H3b, qwb, qb, kb, vb, Qb, Kb, Vb);

    fmha2_kernel<<<dim3(NPTS / QR, B, NSPL), 256, 0, stream>>>(Qb, Kb, Vb, Acc0, Acc1, Acc2, Acc3, Mb, Lb);
    fmha_combine_kernel<<<dim3(NTOT * HID / 256), 256, 0, stream>>>(Acc0, Acc1, Acc2, Acc3, Mb, Lb, OBF);

    gemm_kernel<128, 3><<<dim3(NTOT / 64, 4), 256, 0, stream>>>(OBF, fwb, fb, H3b, H4b, 256, nullptr);
    gemm_kernel<256, 5><<<dim3(NTOT / 64, 1), 256, 0, stream>>>(H4b, aw1b, ab1,
                                                                (const unsigned short*)aw2, s, 64, (float*)ab2);

    softmax_w_kernel<<<B, 256, 0, stream>>>(s);
    pool3_kernel<<<dim3(64, B), 256, 0, stream>>>(H4b, s, pooled);
    fc_kernel<<<B, 256, 0, stream>>>(pooled, fcw, fcb, (float*)d_out);

    (void)in_sizes; (void)n_in; (void)out_size; (void)ws_size;
}